// Round 1
// baseline (938.049 us; speedup 1.0000x reference)
//
#include <hip/hip_runtime.h>

// GNN encoder: input MLP + LN, 2x SAGEConv(mean) + ReLU + residual + LN, classifier MLP.
// Round 0: correctness-first f32 baseline.
//   - aggregation: edge-parallel float atomicAdd scatter (msg), int histogram for degrees
//   - dense: templated matmul kernel, W in LDS, 4 rows/wave, 4 cols/lane, fused epilogues

namespace {

constexpr int NN = 50000;
constexpr int EE = 640000;
constexpr int HH = 128;
constexpr int CC = 40;

constexpr int POST_NONE = 0, POST_RELU = 1, POST_LN = 2, POST_COMBINE = 3;

__global__ void k_degree(const int* __restrict__ ei, int* __restrict__ cnt) {
  int e = blockIdx.x * 256 + threadIdx.x;
  if (e < EE) atomicAdd(&cnt[ei[EE + e]], 1);
}

__global__ void k_invcnt(const int* __restrict__ cnt, float* __restrict__ inv) {
  int i = blockIdx.x * 256 + threadIdx.x;
  if (i < NN) inv[i] = cnt[i] > 0 ? 1.0f / (float)cnt[i] : 0.0f;
}

// one thread per (edge, col): read h[src][c], atomicAdd into msg[dst][c]
__global__ void k_scatter_add(const float* __restrict__ h, const int* __restrict__ ei,
                              float* __restrict__ msg) {
  long long idx = (long long)blockIdx.x * 256 + threadIdx.x;
  int e = (int)(idx >> 7);
  int c = (int)(idx & 127);
  if (e >= EE) return;
  int s = ei[e];
  int d = ei[EE + e];
  atomicAdd(&msg[(size_t)d * HH + c], h[(size_t)s * HH + c]);
}

// out[N,NC] = post( A[N,H] @ W[H,NC] + bias )
// POST_COMBINE: v = relu(tmp + acc); out = LN(resid + v)      (bias==nullptr)
// POST_LN:      out = LN(acc + bias)
// SCALE_IN: A row r scaled by inv_cnt[r] during staging (mean aggregation)
template <int NC, int POST, bool SCALE_IN>
__global__ __launch_bounds__(256) void k_matmul(
    const float* __restrict__ A, const float* __restrict__ W,
    const float* __restrict__ bias, const float* __restrict__ inv_cnt,
    const float* __restrict__ tmp, const float* __restrict__ resid,
    const float* __restrict__ lg, const float* __restrict__ lb,
    float* __restrict__ out) {
  __shared__ float w_lds[HH * NC];
  __shared__ float row_lds[4][4][HH];
  const int tid = threadIdx.x;
  const int wv = tid >> 6;
  const int ln = tid & 63;

  for (int i = tid; i < HH * NC / 4; i += 256)
    reinterpret_cast<float4*>(w_lds)[i] = reinterpret_cast<const float4*>(W)[i];
  __syncthreads();

  const int row0 = blockIdx.x * 64;
  for (int rr = 0; rr < 64; rr += 16) {
    const int rbase = row0 + rr + wv * 4;
    {  // stage 4 rows per wave: lane covers row (ln>>4), cols (ln&15)*8..+7
      const int r = rbase + (ln >> 4);
      const int rs = r < NN ? r : NN - 1;
      const float4* src = reinterpret_cast<const float4*>(A + (size_t)rs * HH + (ln & 15) * 8);
      float4 v0 = src[0], v1 = src[1];
      if (SCALE_IN) {
        const float sc = inv_cnt[rs];
        v0.x *= sc; v0.y *= sc; v0.z *= sc; v0.w *= sc;
        v1.x *= sc; v1.y *= sc; v1.z *= sc; v1.w *= sc;
      }
      float4* dst = reinterpret_cast<float4*>(&row_lds[wv][ln >> 4][(ln & 15) * 8]);
      dst[0] = v0; dst[1] = v1;
    }
    __syncthreads();

    if constexpr (NC == HH) {
      const int rg = ln >> 5;   // half-wave picks row pair
      const int cg = ln & 31;   // 4 cols per lane
      float acc[2][4] = {};
      const float* rA = row_lds[wv][rg * 2 + 0];
      const float* rB = row_lds[wv][rg * 2 + 1];
#pragma unroll 8
      for (int k = 0; k < HH; ++k) {
        const float a0 = rA[k];
        const float a1 = rB[k];
        const float4 w = *reinterpret_cast<const float4*>(&w_lds[k * NC + cg * 4]);
        acc[0][0] += a0 * w.x; acc[0][1] += a0 * w.y; acc[0][2] += a0 * w.z; acc[0][3] += a0 * w.w;
        acc[1][0] += a1 * w.x; acc[1][1] += a1 * w.y; acc[1][2] += a1 * w.z; acc[1][3] += a1 * w.w;
      }
      if (bias) {
        const float4 bb = *reinterpret_cast<const float4*>(&bias[cg * 4]);
        for (int i = 0; i < 2; ++i) {
          acc[i][0] += bb.x; acc[i][1] += bb.y; acc[i][2] += bb.z; acc[i][3] += bb.w;
        }
      }
      for (int i = 0; i < 2; ++i) {
        const int r = rbase + rg * 2 + i;
        const int rs = r < NN ? r : NN - 1;
        float v[4];
        if constexpr (POST == POST_COMBINE) {
          const float4 t  = *reinterpret_cast<const float4*>(&tmp  [(size_t)rs * HH + cg * 4]);
          const float4 rd = *reinterpret_cast<const float4*>(&resid[(size_t)rs * HH + cg * 4]);
          v[0] = rd.x + fmaxf(t.x + acc[i][0], 0.0f);
          v[1] = rd.y + fmaxf(t.y + acc[i][1], 0.0f);
          v[2] = rd.z + fmaxf(t.z + acc[i][2], 0.0f);
          v[3] = rd.w + fmaxf(t.w + acc[i][3], 0.0f);
        } else if constexpr (POST == POST_RELU) {
          for (int j = 0; j < 4; ++j) v[j] = fmaxf(acc[i][j], 0.0f);
        } else {
          for (int j = 0; j < 4; ++j) v[j] = acc[i][j];
        }
        if constexpr (POST == POST_LN || POST == POST_COMBINE) {
          float s = v[0] + v[1] + v[2] + v[3];
          for (int m = 1; m < 32; m <<= 1) s += __shfl_xor(s, m, 64);
          const float mu = s * (1.0f / HH);
          float q = 0.0f;
          for (int j = 0; j < 4; ++j) { const float d = v[j] - mu; q += d * d; }
          for (int m = 1; m < 32; m <<= 1) q += __shfl_xor(q, m, 64);
          const float istd = rsqrtf(q * (1.0f / HH) + 1e-5f);
          if (r < NN) {
            const float4 gg = *reinterpret_cast<const float4*>(&lg[cg * 4]);
            const float4 b2 = *reinterpret_cast<const float4*>(&lb[cg * 4]);
            float4 o;
            o.x = (v[0] - mu) * istd * gg.x + b2.x;
            o.y = (v[1] - mu) * istd * gg.y + b2.y;
            o.z = (v[2] - mu) * istd * gg.z + b2.z;
            o.w = (v[3] - mu) * istd * gg.w + b2.w;
            *reinterpret_cast<float4*>(&out[(size_t)r * HH + cg * 4]) = o;
          }
        } else {
          if (r < NN) {
            float4 o = {v[0], v[1], v[2], v[3]};
            *reinterpret_cast<float4*>(&out[(size_t)r * HH + cg * 4]) = o;
          }
        }
      }
    } else {
      // narrow output (classifier logits): 1 col per lane, 4 rows
      const int c = ln < NC ? ln : NC - 1;
      float acc[4] = {0, 0, 0, 0};
#pragma unroll 4
      for (int k = 0; k < HH; ++k) {
        const float w = w_lds[k * NC + c];
        acc[0] += row_lds[wv][0][k] * w;
        acc[1] += row_lds[wv][1][k] * w;
        acc[2] += row_lds[wv][2][k] * w;
        acc[3] += row_lds[wv][3][k] * w;
      }
      const float bb = bias ? bias[c] : 0.0f;
      if (ln < NC) {
        for (int i = 0; i < 4; ++i) {
          const int r = rbase + i;
          if (r < NN) out[(size_t)r * NC + c] = acc[i] + bb;
        }
      }
    }
  }
}

}  // namespace

extern "C" void kernel_launch(void* const* d_in, const int* in_sizes, int n_in,
                              void* d_out, int out_size, void* d_ws, size_t ws_size,
                              hipStream_t stream) {
  (void)in_sizes; (void)n_in; (void)out_size; (void)ws_size;
  const float* x   = (const float*)d_in[0];
  const int*   ei  = (const int*)d_in[1];
  const float* pw1 = (const float*)d_in[2];
  const float* pb1 = (const float*)d_in[3];
  const float* pw2 = (const float*)d_in[4];
  const float* pb2 = (const float*)d_in[5];
  const float* ing = (const float*)d_in[6];
  const float* inb = (const float*)d_in[7];
  const float* swl = (const float*)d_in[8];
  const float* sbl = (const float*)d_in[9];
  const float* swr = (const float*)d_in[10];
  const float* lng = (const float*)d_in[11];
  const float* lnb = (const float*)d_in[12];
  const float* cw1 = (const float*)d_in[13];
  const float* cb1 = (const float*)d_in[14];
  const float* cw2 = (const float*)d_in[15];
  const float* cb2 = (const float*)d_in[16];

  float* out_logits = (float*)d_out;
  float* out_h = out_logits + (size_t)NN * CC;

  float* b0 = (float*)d_ws;                   // h
  float* b1 = b0 + (size_t)NN * HH;           // tmp / t1 / t3
  float* b2 = b1 + (size_t)NN * HH;           // msg (scatter target)
  int*   cnt = (int*)(b2 + (size_t)NN * HH);
  float* inv = (float*)(cnt + NN);

  hipMemsetAsync(cnt, 0, NN * sizeof(int), stream);
  k_degree<<<(EE + 255) / 256, 256, 0, stream>>>(ei, cnt);
  k_invcnt<<<(NN + 255) / 256, 256, 0, stream>>>(cnt, inv);

  const int MMG = (NN + 63) / 64;
  // t1 = relu(x @ pw1 + pb1)
  k_matmul<HH, POST_RELU, false><<<MMG, 256, 0, stream>>>(
      x, pw1, pb1, nullptr, nullptr, nullptr, nullptr, nullptr, b1);
  // h = LN(t1 @ pw2 + pb2)
  k_matmul<HH, POST_LN, false><<<MMG, 256, 0, stream>>>(
      b1, pw2, pb2, nullptr, nullptr, nullptr, ing, inb, b0);

  for (int l = 0; l < 2; ++l) {
    const float* wl = swl + (size_t)l * HH * HH;
    const float* bl = sbl + (size_t)l * HH;
    const float* wr = swr + (size_t)l * HH * HH;
    const float* g  = lng + (size_t)l * HH;
    const float* bb = lnb + (size_t)l * HH;
    float* hout = (l == 0) ? b0 : out_h;

    hipMemsetAsync(b2, 0, (size_t)NN * HH * sizeof(float), stream);
    k_scatter_add<<<EE / 2, 256, 0, stream>>>(b0, ei, b2);
    // tmp = agg @ wl + bl   (agg = msg * inv_cnt, fused into staging)
    k_matmul<HH, POST_NONE, true><<<MMG, 256, 0, stream>>>(
        b2, wl, bl, inv, nullptr, nullptr, nullptr, nullptr, b1);
    // h = LN(h + relu(tmp + h @ wr))
    k_matmul<HH, POST_COMBINE, false><<<MMG, 256, 0, stream>>>(
        b0, wr, nullptr, nullptr, b1, b0, g, bb, hout);
  }

  // classifier: t3 = relu(h @ cw1 + cb1); logits = t3 @ cw2 + cb2
  k_matmul<HH, POST_RELU, false><<<MMG, 256, 0, stream>>>(
      out_h, cw1, cb1, nullptr, nullptr, nullptr, nullptr, nullptr, b1);
  k_matmul<CC, POST_NONE, false><<<MMG, 256, 0, stream>>>(
      b1, cw2, cb2, nullptr, nullptr, nullptr, nullptr, nullptr, out_logits);
}

// Round 2
// 516.992 us; speedup vs baseline: 1.8144x; 1.8144x over previous
//
#include <hip/hip_runtime.h>

// GNN encoder: input MLP + LN, 2x SAGEConv(mean) + ReLU + residual + LN, classifier MLP.
// Round 1: replace atomic scatter aggregation (490 MB HBM RMW traffic, 2x271us)
// with CSR build + wave-per-node gather (writes agg exactly once, gathers hit L2/L3).

namespace {

constexpr int NN = 50000;
constexpr int EE = 640000;
constexpr int HH = 128;
constexpr int CC = 40;
constexpr int SCAN_NB = (NN + 255) / 256;  // 196

constexpr int POST_NONE = 0, POST_RELU = 1, POST_LN = 2, POST_COMBINE = 3;

__global__ void k_degree(const int* __restrict__ ei, int* __restrict__ cnt) {
  int e = blockIdx.x * 256 + threadIdx.x;
  if (e < EE) atomicAdd(&cnt[ei[EE + e]], 1);
}

__global__ void k_invcnt(const int* __restrict__ cnt, float* __restrict__ inv) {
  int i = blockIdx.x * 256 + threadIdx.x;
  if (i < NN) inv[i] = cnt[i] > 0 ? 1.0f / (float)cnt[i] : 0.0f;
}

// --- 3-kernel exclusive scan of cnt[NN] -> rowptr[NN+1] ---
__global__ void k_scan_block(const int* __restrict__ cnt, int* __restrict__ rowptr,
                             int* __restrict__ bsum) {
  __shared__ int s[256];
  const int t = threadIdx.x;
  const int i = blockIdx.x * 256 + t;
  const int v = i < NN ? cnt[i] : 0;
  s[t] = v;
  __syncthreads();
  for (int off = 1; off < 256; off <<= 1) {
    int add = t >= off ? s[t - off] : 0;
    __syncthreads();
    s[t] += add;
    __syncthreads();
  }
  if (i < NN) rowptr[i] = s[t] - v;  // exclusive within block
  if (t == 255) bsum[blockIdx.x] = s[255];
}

__global__ void k_scan_tops(int* __restrict__ bsum) {
  __shared__ int s[256];
  const int t = threadIdx.x;
  const int v = t < SCAN_NB ? bsum[t] : 0;
  s[t] = v;
  __syncthreads();
  for (int off = 1; off < 256; off <<= 1) {
    int add = t >= off ? s[t - off] : 0;
    __syncthreads();
    s[t] += add;
    __syncthreads();
  }
  if (t < SCAN_NB) bsum[t] = s[t] - v;  // exclusive block offsets
}

__global__ void k_scan_add(int* __restrict__ rowptr, const int* __restrict__ bsum) {
  const int i = blockIdx.x * 256 + threadIdx.x;
  if (i < NN) rowptr[i] += bsum[blockIdx.x];
  if (i == 0) rowptr[NN] = EE;
}

// bucket edges by dst: col[rowptr[d] + pos] = src
__global__ void k_fill(const int* __restrict__ ei, const int* __restrict__ rowptr,
                       int* __restrict__ cursor, int* __restrict__ col) {
  int e = blockIdx.x * 256 + threadIdx.x;
  if (e >= EE) return;
  int s = ei[e];
  int d = ei[EE + e];
  int pos = atomicAdd(&cursor[d], 1);
  col[rowptr[d] + pos] = s;
}

// one wave per node: agg[node] = inv[node] * sum_{e in-edges} h[col[e]]
__global__ __launch_bounds__(256) void k_gather(
    const float* __restrict__ h, const int* __restrict__ rowptr,
    const int* __restrict__ col, const float* __restrict__ inv,
    float* __restrict__ agg) {
  const int tid = threadIdx.x;
  const int wv = tid >> 6;
  const int ln = tid & 63;
  const int node = blockIdx.x * 4 + wv;
  if (node >= NN) return;
  const int start = rowptr[node];
  const int end = rowptr[node + 1];
  float ax = 0.0f, ay = 0.0f;
  int i = start;
  for (; i + 4 <= end; i += 4) {
    const int s0 = col[i], s1 = col[i + 1], s2 = col[i + 2], s3 = col[i + 3];
    const float2 v0 = *reinterpret_cast<const float2*>(&h[(size_t)s0 * HH + ln * 2]);
    const float2 v1 = *reinterpret_cast<const float2*>(&h[(size_t)s1 * HH + ln * 2]);
    const float2 v2 = *reinterpret_cast<const float2*>(&h[(size_t)s2 * HH + ln * 2]);
    const float2 v3 = *reinterpret_cast<const float2*>(&h[(size_t)s3 * HH + ln * 2]);
    ax += v0.x + v1.x + v2.x + v3.x;
    ay += v0.y + v1.y + v2.y + v3.y;
  }
  for (; i < end; ++i) {
    const float2 v = *reinterpret_cast<const float2*>(&h[(size_t)col[i] * HH + ln * 2]);
    ax += v.x;
    ay += v.y;
  }
  const float sc = inv[node];
  float2 o;
  o.x = ax * sc;
  o.y = ay * sc;
  *reinterpret_cast<float2*>(&agg[(size_t)node * HH + ln * 2]) = o;
}

// out[N,NC] = post( A[N,H] @ W[H,NC] + bias )
template <int NC, int POST, bool SCALE_IN>
__global__ __launch_bounds__(256) void k_matmul(
    const float* __restrict__ A, const float* __restrict__ W,
    const float* __restrict__ bias, const float* __restrict__ inv_cnt,
    const float* __restrict__ tmp, const float* __restrict__ resid,
    const float* __restrict__ lg, const float* __restrict__ lb,
    float* __restrict__ out) {
  __shared__ float w_lds[HH * NC];
  __shared__ float row_lds[4][4][HH];
  const int tid = threadIdx.x;
  const int wv = tid >> 6;
  const int ln = tid & 63;

  for (int i = tid; i < HH * NC / 4; i += 256)
    reinterpret_cast<float4*>(w_lds)[i] = reinterpret_cast<const float4*>(W)[i];
  __syncthreads();

  const int row0 = blockIdx.x * 64;
  for (int rr = 0; rr < 64; rr += 16) {
    const int rbase = row0 + rr + wv * 4;
    {
      const int r = rbase + (ln >> 4);
      const int rs = r < NN ? r : NN - 1;
      const float4* src = reinterpret_cast<const float4*>(A + (size_t)rs * HH + (ln & 15) * 8);
      float4 v0 = src[0], v1 = src[1];
      if (SCALE_IN) {
        const float sc = inv_cnt[rs];
        v0.x *= sc; v0.y *= sc; v0.z *= sc; v0.w *= sc;
        v1.x *= sc; v1.y *= sc; v1.z *= sc; v1.w *= sc;
      }
      float4* dst = reinterpret_cast<float4*>(&row_lds[wv][ln >> 4][(ln & 15) * 8]);
      dst[0] = v0; dst[1] = v1;
    }
    __syncthreads();

    if constexpr (NC == HH) {
      const int rg = ln >> 5;
      const int cg = ln & 31;
      float acc[2][4] = {};
      const float* rA = row_lds[wv][rg * 2 + 0];
      const float* rB = row_lds[wv][rg * 2 + 1];
#pragma unroll 8
      for (int k = 0; k < HH; ++k) {
        const float a0 = rA[k];
        const float a1 = rB[k];
        const float4 w = *reinterpret_cast<const float4*>(&w_lds[k * NC + cg * 4]);
        acc[0][0] += a0 * w.x; acc[0][1] += a0 * w.y; acc[0][2] += a0 * w.z; acc[0][3] += a0 * w.w;
        acc[1][0] += a1 * w.x; acc[1][1] += a1 * w.y; acc[1][2] += a1 * w.z; acc[1][3] += a1 * w.w;
      }
      if (bias) {
        const float4 bb = *reinterpret_cast<const float4*>(&bias[cg * 4]);
        for (int i = 0; i < 2; ++i) {
          acc[i][0] += bb.x; acc[i][1] += bb.y; acc[i][2] += bb.z; acc[i][3] += bb.w;
        }
      }
      for (int i = 0; i < 2; ++i) {
        const int r = rbase + rg * 2 + i;
        const int rs = r < NN ? r : NN - 1;
        float v[4];
        if constexpr (POST == POST_COMBINE) {
          const float4 t  = *reinterpret_cast<const float4*>(&tmp  [(size_t)rs * HH + cg * 4]);
          const float4 rd = *reinterpret_cast<const float4*>(&resid[(size_t)rs * HH + cg * 4]);
          v[0] = rd.x + fmaxf(t.x + acc[i][0], 0.0f);
          v[1] = rd.y + fmaxf(t.y + acc[i][1], 0.0f);
          v[2] = rd.z + fmaxf(t.z + acc[i][2], 0.0f);
          v[3] = rd.w + fmaxf(t.w + acc[i][3], 0.0f);
        } else if constexpr (POST == POST_RELU) {
          for (int j = 0; j < 4; ++j) v[j] = fmaxf(acc[i][j], 0.0f);
        } else {
          for (int j = 0; j < 4; ++j) v[j] = acc[i][j];
        }
        if constexpr (POST == POST_LN || POST == POST_COMBINE) {
          float s = v[0] + v[1] + v[2] + v[3];
          for (int m = 1; m < 32; m <<= 1) s += __shfl_xor(s, m, 64);
          const float mu = s * (1.0f / HH);
          float q = 0.0f;
          for (int j = 0; j < 4; ++j) { const float d = v[j] - mu; q += d * d; }
          for (int m = 1; m < 32; m <<= 1) q += __shfl_xor(q, m, 64);
          const float istd = rsqrtf(q * (1.0f / HH) + 1e-5f);
          if (r < NN) {
            const float4 gg = *reinterpret_cast<const float4*>(&lg[cg * 4]);
            const float4 b2 = *reinterpret_cast<const float4*>(&lb[cg * 4]);
            float4 o;
            o.x = (v[0] - mu) * istd * gg.x + b2.x;
            o.y = (v[1] - mu) * istd * gg.y + b2.y;
            o.z = (v[2] - mu) * istd * gg.z + b2.z;
            o.w = (v[3] - mu) * istd * gg.w + b2.w;
            *reinterpret_cast<float4*>(&out[(size_t)r * HH + cg * 4]) = o;
          }
        } else {
          if (r < NN) {
            float4 o = {v[0], v[1], v[2], v[3]};
            *reinterpret_cast<float4*>(&out[(size_t)r * HH + cg * 4]) = o;
          }
        }
      }
    } else {
      const int c = ln < NC ? ln : NC - 1;
      float acc[4] = {0, 0, 0, 0};
#pragma unroll 4
      for (int k = 0; k < HH; ++k) {
        const float w = w_lds[k * NC + c];
        acc[0] += row_lds[wv][0][k] * w;
        acc[1] += row_lds[wv][1][k] * w;
        acc[2] += row_lds[wv][2][k] * w;
        acc[3] += row_lds[wv][3][k] * w;
      }
      const float bb = bias ? bias[c] : 0.0f;
      if (ln < NC) {
        for (int i = 0; i < 4; ++i) {
          const int r = rbase + i;
          if (r < NN) out[(size_t)r * NC + c] = acc[i] + bb;
        }
      }
    }
  }
}

}  // namespace

extern "C" void kernel_launch(void* const* d_in, const int* in_sizes, int n_in,
                              void* d_out, int out_size, void* d_ws, size_t ws_size,
                              hipStream_t stream) {
  (void)in_sizes; (void)n_in; (void)out_size; (void)ws_size;
  const float* x   = (const float*)d_in[0];
  const int*   ei  = (const int*)d_in[1];
  const float* pw1 = (const float*)d_in[2];
  const float* pb1 = (const float*)d_in[3];
  const float* pw2 = (const float*)d_in[4];
  const float* pb2 = (const float*)d_in[5];
  const float* ing = (const float*)d_in[6];
  const float* inb = (const float*)d_in[7];
  const float* swl = (const float*)d_in[8];
  const float* sbl = (const float*)d_in[9];
  const float* swr = (const float*)d_in[10];
  const float* lng = (const float*)d_in[11];
  const float* lnb = (const float*)d_in[12];
  const float* cw1 = (const float*)d_in[13];
  const float* cb1 = (const float*)d_in[14];
  const float* cw2 = (const float*)d_in[15];
  const float* cb2 = (const float*)d_in[16];

  float* out_logits = (float*)d_out;
  float* out_h = out_logits + (size_t)NN * CC;

  float* b0 = (float*)d_ws;                   // h
  float* b1 = b0 + (size_t)NN * HH;           // tmp / t1 / t3
  float* b2 = b1 + (size_t)NN * HH;           // agg
  int*   cnt    = (int*)(b2 + (size_t)NN * HH);
  float* inv    = (float*)(cnt + NN);
  int*   rowptr = (int*)(inv + NN);           // NN+1
  int*   cursor = rowptr + NN + 1;            // NN
  int*   bsum   = cursor + NN;                // SCAN_NB
  int*   col    = bsum + 256;                 // EE

  // ---- CSR build (once; reused by both layers) ----
  hipMemsetAsync(cnt, 0, NN * sizeof(int), stream);
  hipMemsetAsync(cursor, 0, NN * sizeof(int), stream);
  k_degree<<<(EE + 255) / 256, 256, 0, stream>>>(ei, cnt);
  k_invcnt<<<(NN + 255) / 256, 256, 0, stream>>>(cnt, inv);
  k_scan_block<<<SCAN_NB, 256, 0, stream>>>(cnt, rowptr, bsum);
  k_scan_tops<<<1, 256, 0, stream>>>(bsum);
  k_scan_add<<<SCAN_NB, 256, 0, stream>>>(rowptr, bsum);
  k_fill<<<(EE + 255) / 256, 256, 0, stream>>>(ei, rowptr, cursor, col);

  const int MMG = (NN + 63) / 64;
  // t1 = relu(x @ pw1 + pb1)
  k_matmul<HH, POST_RELU, false><<<MMG, 256, 0, stream>>>(
      x, pw1, pb1, nullptr, nullptr, nullptr, nullptr, nullptr, b1);
  // h = LN(t1 @ pw2 + pb2)
  k_matmul<HH, POST_LN, false><<<MMG, 256, 0, stream>>>(
      b1, pw2, pb2, nullptr, nullptr, nullptr, ing, inb, b0);

  for (int l = 0; l < 2; ++l) {
    const float* wl = swl + (size_t)l * HH * HH;
    const float* bl = sbl + (size_t)l * HH;
    const float* wr = swr + (size_t)l * HH * HH;
    const float* g  = lng + (size_t)l * HH;
    const float* bb = lnb + (size_t)l * HH;
    float* hout = (l == 0) ? b0 : out_h;

    // agg = mean of in-neighbors (gather over CSR, inv fused)
    k_gather<<<(NN + 3) / 4, 256, 0, stream>>>(b0, rowptr, col, inv, b2);
    // tmp = agg @ wl + bl
    k_matmul<HH, POST_NONE, false><<<MMG, 256, 0, stream>>>(
        b2, wl, bl, nullptr, nullptr, nullptr, nullptr, nullptr, b1);
    // h = LN(h + relu(tmp + h @ wr))
    k_matmul<HH, POST_COMBINE, false><<<MMG, 256, 0, stream>>>(
        b0, wr, nullptr, nullptr, b1, b0, g, bb, hout);
  }

  // classifier
  k_matmul<HH, POST_RELU, false><<<MMG, 256, 0, stream>>>(
      out_h, cw1, cb1, nullptr, nullptr, nullptr, nullptr, nullptr, b1);
  k_matmul<CC, POST_NONE, false><<<MMG, 256, 0, stream>>>(
      b1, cw2, cb2, nullptr, nullptr, nullptr, nullptr, nullptr, out_logits);
}

// Round 3
// 356.204 us; speedup vs baseline: 2.6335x; 1.4514x over previous
//
#include <hip/hip_runtime.h>

// GNN encoder: input MLP + LN, 2x SAGEConv(mean) + ReLU + residual + LN, classifier MLP.
// Round 2: all dense matmuls -> bf16 MFMA (16x16x32, f32 accum), zero LDS:
//   W stored transposed (WT[n][k] bf16) so A and B fragments are contiguous 16B
//   global loads (slot-pairing makes any shared bijective k-map correct).
//   Fused epilogues use the m89-verified C/D layout (col=lane&15, row=(lane>>4)*4+reg).
//   Gather reads bf16 h (half traffic), accumulates f32.

namespace {

constexpr int NN = 50000;
constexpr int EE = 640000;
constexpr int HH = 128;
constexpr int CC = 40;
constexpr int SCAN_NB = (NN + 255) / 256;  // 196

constexpr int POST_NONE = 0, POST_RELU = 1, POST_LN = 2, POST_COMBINE = 3;

typedef unsigned short u16;
typedef __attribute__((ext_vector_type(8))) short s16x8;
typedef __attribute__((ext_vector_type(8))) unsigned short u16x8;
typedef __attribute__((ext_vector_type(4))) float f32x4;

__device__ __forceinline__ float b2f(u16 h) {
  unsigned int u = ((unsigned int)h) << 16;
  return __builtin_bit_cast(float, u);
}
__device__ __forceinline__ u16 f2b(float f) {
  unsigned int u = __builtin_bit_cast(unsigned int, f);
  u += 0x7FFFu + ((u >> 16) & 1u);
  return (u16)(u >> 16);
}

// ---------------- CSR build ----------------
__global__ void k_degree(const int* __restrict__ ei, int* __restrict__ cnt) {
  int e = blockIdx.x * 256 + threadIdx.x;
  if (e < EE) atomicAdd(&cnt[ei[EE + e]], 1);
}

__global__ void k_invcnt(const int* __restrict__ cnt, float* __restrict__ inv) {
  int i = blockIdx.x * 256 + threadIdx.x;
  if (i < NN) inv[i] = cnt[i] > 0 ? 1.0f / (float)cnt[i] : 0.0f;
}

__global__ void k_scan_block(const int* __restrict__ cnt, int* __restrict__ rowptr,
                             int* __restrict__ bsum) {
  __shared__ int s[256];
  const int t = threadIdx.x;
  const int i = blockIdx.x * 256 + t;
  const int v = i < NN ? cnt[i] : 0;
  s[t] = v;
  __syncthreads();
  for (int off = 1; off < 256; off <<= 1) {
    int add = t >= off ? s[t - off] : 0;
    __syncthreads();
    s[t] += add;
    __syncthreads();
  }
  if (i < NN) rowptr[i] = s[t] - v;
  if (t == 255) bsum[blockIdx.x] = s[255];
}

__global__ void k_scan_tops(int* __restrict__ bsum) {
  __shared__ int s[256];
  const int t = threadIdx.x;
  const int v = t < SCAN_NB ? bsum[t] : 0;
  s[t] = v;
  __syncthreads();
  for (int off = 1; off < 256; off <<= 1) {
    int add = t >= off ? s[t - off] : 0;
    __syncthreads();
    s[t] += add;
    __syncthreads();
  }
  if (t < SCAN_NB) bsum[t] = s[t] - v;
}

__global__ void k_scan_add(int* __restrict__ rowptr, const int* __restrict__ bsum) {
  const int i = blockIdx.x * 256 + threadIdx.x;
  if (i < NN) rowptr[i] += bsum[blockIdx.x];
  if (i == 0) rowptr[NN] = EE;
}

__global__ void k_fill(const int* __restrict__ ei, const int* __restrict__ rowptr,
                       int* __restrict__ cursor, int* __restrict__ col) {
  int e = blockIdx.x * 256 + threadIdx.x;
  if (e >= EE) return;
  int s = ei[e];
  int d = ei[EE + e];
  int pos = atomicAdd(&cursor[d], 1);
  col[rowptr[d] + pos] = s;
}

// ---------------- conversions ----------------
__global__ void k_cast8(const float* __restrict__ src, u16* __restrict__ dst, int n8) {
  int t = blockIdx.x * 256 + threadIdx.x;
  if (t >= n8) return;
  const float4* s4 = reinterpret_cast<const float4*>(src + (size_t)t * 8);
  float4 a = s4[0], b = s4[1];
  u16x8 o;
  o[0] = f2b(a.x); o[1] = f2b(a.y); o[2] = f2b(a.z); o[3] = f2b(a.w);
  o[4] = f2b(b.x); o[5] = f2b(b.y); o[6] = f2b(b.z); o[7] = f2b(b.w);
  *reinterpret_cast<u16x8*>(dst + (size_t)t * 8) = o;
}

// transpose+cast all weights into wt slots {pw1,pw2,wl0,wl1,wr0,wr1,cw1,cw2}
__global__ void k_prep_w(const float* __restrict__ pw1, const float* __restrict__ pw2,
                         const float* __restrict__ swl, const float* __restrict__ swr,
                         const float* __restrict__ cw1, const float* __restrict__ cw2,
                         u16* __restrict__ wt) {
  int flat = blockIdx.x * 256 + threadIdx.x;
  const int SEVEN = 7 * 16384;
  if (flat < SEVEN) {
    int id = flat >> 14;
    int off = flat & 16383;
    int n = off >> 7, k = off & 127;
    const float* s;
    switch (id) {
      case 0: s = pw1; break;
      case 1: s = pw2; break;
      case 2: s = swl; break;
      case 3: s = swl + 16384; break;
      case 4: s = swr; break;
      case 5: s = swr + 16384; break;
      default: s = cw1; break;
    }
    wt[(size_t)id * 16384 + n * 128 + k] = f2b(s[k * 128 + n]);
  } else {
    int off = flat - SEVEN;
    if (off < CC * 128) {
      int n = off >> 7, k = off & 127;
      wt[(size_t)7 * 16384 + n * 128 + k] = f2b(cw2[k * CC + n]);
    }
  }
}

// ---------------- aggregation: wave per node, 2 edges per iter ----------------
__global__ __launch_bounds__(256) void k_gather_bf(
    const u16* __restrict__ hb, const int* __restrict__ rowptr,
    const int* __restrict__ col, const float* __restrict__ inv,
    u16* __restrict__ agg) {
  const int tid = threadIdx.x;
  const int wv = tid >> 6, ln = tid & 63;
  const int node = blockIdx.x * 4 + wv;
  if (node >= NN) return;
  const int start = rowptr[node];
  const int end = rowptr[node + 1];
  const int half = ln >> 5;
  const int cl = (ln & 31) * 4;
  float a0 = 0.f, a1 = 0.f, a2 = 0.f, a3 = 0.f;
  int i = start;
  for (; i + 2 <= end; i += 2) {
    int s = col[i + half];
    ushort4 v = *reinterpret_cast<const ushort4*>(&hb[(size_t)s * HH + cl]);
    a0 += b2f(v.x); a1 += b2f(v.y); a2 += b2f(v.z); a3 += b2f(v.w);
  }
  if (i < end && half == 0) {
    int s = col[i];
    ushort4 v = *reinterpret_cast<const ushort4*>(&hb[(size_t)s * HH + cl]);
    a0 += b2f(v.x); a1 += b2f(v.y); a2 += b2f(v.z); a3 += b2f(v.w);
  }
  a0 += __shfl_xor(a0, 32);
  a1 += __shfl_xor(a1, 32);
  a2 += __shfl_xor(a2, 32);
  a3 += __shfl_xor(a3, 32);
  if (half == 0) {
    const float sc = inv[node];
    ushort4 o;
    o.x = f2b(a0 * sc); o.y = f2b(a1 * sc); o.z = f2b(a2 * sc); o.w = f2b(a3 * sc);
    *reinterpret_cast<ushort4*>(&agg[(size_t)node * HH + cl]) = o;
  }
}

// ---------------- MFMA matmul with fused epilogue ----------------
// out[N,NC] = post( A[N,128](bf16) @ WT[NC,128]^T(bf16) + bias )
// block = 64 rows (4 waves x 16 rows), full NC width per wave, no LDS.
template <int NC, int POST, bool WF32, bool WBF16>
__global__ __launch_bounds__(256) void k_mfma(
    const u16* __restrict__ A, const u16* __restrict__ WT,
    const float* __restrict__ bias, const float* __restrict__ tmp,
    const float* __restrict__ resid, const float* __restrict__ lg,
    const float* __restrict__ lb, float* __restrict__ outf,
    u16* __restrict__ outb) {
  constexpr int NCF = (NC + 15) / 16;
  const int tid = threadIdx.x;
  const int wv = tid >> 6, ln = tid & 63;
  const int lrow = ln & 15, kg = ln >> 4;
  const int row0 = blockIdx.x * 64 + wv * 16;
  const int ar = min(row0 + lrow, NN - 1);
  const u16* ap = A + (size_t)ar * 128 + kg * 8;

  int bn[NCF];
#pragma unroll
  for (int cf = 0; cf < NCF; ++cf) {
    int n = cf * 16 + lrow;
    bn[cf] = (NC < 128 && n >= NC) ? NC - 1 : n;
  }

  f32x4 acc[NCF];
#pragma unroll
  for (int cf = 0; cf < NCF; ++cf) acc[cf] = (f32x4){0.f, 0.f, 0.f, 0.f};

#pragma unroll
  for (int ks = 0; ks < 4; ++ks) {
    s16x8 af = *reinterpret_cast<const s16x8*>(ap + ks * 32);
#pragma unroll
    for (int cf = 0; cf < NCF; ++cf) {
      s16x8 bf = *reinterpret_cast<const s16x8*>(WT + (size_t)bn[cf] * 128 + ks * 32 + kg * 8);
      acc[cf] = __builtin_amdgcn_mfma_f32_16x16x32_bf16(af, bf, acc[cf], 0, 0, 0);
    }
  }

  float bb[NCF];
#pragma unroll
  for (int cf = 0; cf < NCF; ++cf) bb[cf] = bias ? bias[bn[cf]] : 0.0f;

  float gm[NCF], gb[NCF];
  if constexpr (POST == POST_LN || POST == POST_COMBINE) {
#pragma unroll
    for (int cf = 0; cf < NCF; ++cf) { gm[cf] = lg[bn[cf]]; gb[cf] = lb[bn[cf]]; }
  }

#pragma unroll
  for (int j = 0; j < 4; ++j) {
    const int r = row0 + kg * 4 + j;
    const int rs = r < NN ? r : NN - 1;
    float v[NCF];
#pragma unroll
    for (int cf = 0; cf < NCF; ++cf) v[cf] = acc[cf][j] + bb[cf];
    if constexpr (POST == POST_RELU) {
#pragma unroll
      for (int cf = 0; cf < NCF; ++cf) v[cf] = fmaxf(v[cf], 0.0f);
    } else if constexpr (POST == POST_COMBINE) {
#pragma unroll
      for (int cf = 0; cf < NCF; ++cf) {
        const int c = cf * 16 + lrow;
        const float t = tmp[(size_t)rs * 128 + c];
        const float rd = resid[(size_t)rs * 128 + c];
        v[cf] = rd + fmaxf(t + v[cf], 0.0f);
      }
    }
    if constexpr (POST == POST_LN || POST == POST_COMBINE) {
      float s = 0.f;
#pragma unroll
      for (int cf = 0; cf < NCF; ++cf) s += v[cf];
      s += __shfl_xor(s, 1); s += __shfl_xor(s, 2);
      s += __shfl_xor(s, 4); s += __shfl_xor(s, 8);
      const float mu = s * (1.0f / NC);
      float q = 0.f;
#pragma unroll
      for (int cf = 0; cf < NCF; ++cf) { const float d = v[cf] - mu; q += d * d; }
      q += __shfl_xor(q, 1); q += __shfl_xor(q, 2);
      q += __shfl_xor(q, 4); q += __shfl_xor(q, 8);
      const float istd = rsqrtf(q * (1.0f / NC) + 1e-5f);
#pragma unroll
      for (int cf = 0; cf < NCF; ++cf) v[cf] = (v[cf] - mu) * istd * gm[cf] + gb[cf];
    }
    if (r < NN) {
#pragma unroll
      for (int cf = 0; cf < NCF; ++cf) {
        const int c = cf * 16 + lrow;
        if (NC >= 128 || c < NC) {
          if constexpr (WF32) outf[(size_t)r * NC + c] = v[cf];
          if constexpr (WBF16) outb[(size_t)r * 128 + c] = f2b(v[cf]);
        }
      }
    }
  }
}

}  // namespace

extern "C" void kernel_launch(void* const* d_in, const int* in_sizes, int n_in,
                              void* d_out, int out_size, void* d_ws, size_t ws_size,
                              hipStream_t stream) {
  (void)in_sizes; (void)n_in; (void)out_size; (void)ws_size;
  const float* x   = (const float*)d_in[0];
  const int*   ei  = (const int*)d_in[1];
  const float* pw1 = (const float*)d_in[2];
  const float* pb1 = (const float*)d_in[3];
  const float* pw2 = (const float*)d_in[4];
  const float* pb2 = (const float*)d_in[5];
  const float* ing = (const float*)d_in[6];
  const float* inb = (const float*)d_in[7];
  const float* swl = (const float*)d_in[8];
  const float* sbl = (const float*)d_in[9];
  const float* swr = (const float*)d_in[10];
  const float* lng = (const float*)d_in[11];
  const float* lnb = (const float*)d_in[12];
  const float* cw1 = (const float*)d_in[13];
  const float* cb1 = (const float*)d_in[14];
  const float* cw2 = (const float*)d_in[15];
  const float* cb2 = (const float*)d_in[16];

  float* out_logits = (float*)d_out;
  float* out_h = out_logits + (size_t)NN * CC;

  const size_t NNH = (size_t)NN * HH;  // 6.4M
  float* h    = (float*)d_ws;              // 25.6 MB
  float* tmp  = h + NNH;                   // 25.6 MB
  u16*   hb   = (u16*)(tmp + NNH);         // 12.8 MB
  u16*   bufA = hb + NNH;                  // 12.8 MB (x_bf / agg / t3)
  u16*   bufB = bufA + NNH;                // 12.8 MB (t1)
  u16*   wt   = bufB + NNH;                // 8*16384 u16 = 256 KB
  int*   cnt    = (int*)(wt + 8 * 16384);
  float* inv    = (float*)(cnt + NN);
  int*   rowptr = (int*)(inv + NN);        // NN+1
  int*   cursor = rowptr + NN + 1;         // NN
  int*   bsum   = cursor + NN;             // 256
  int*   colarr = bsum + 256;              // EE

  // ---- CSR build (reused by both layers) ----
  hipMemsetAsync(cnt, 0, NN * sizeof(int), stream);
  hipMemsetAsync(cursor, 0, NN * sizeof(int), stream);
  k_degree<<<(EE + 255) / 256, 256, 0, stream>>>(ei, cnt);
  k_invcnt<<<(NN + 255) / 256, 256, 0, stream>>>(cnt, inv);
  k_scan_block<<<SCAN_NB, 256, 0, stream>>>(cnt, rowptr, bsum);
  k_scan_tops<<<1, 256, 0, stream>>>(bsum);
  k_scan_add<<<SCAN_NB, 256, 0, stream>>>(rowptr, bsum);
  k_fill<<<(EE + 255) / 256, 256, 0, stream>>>(ei, rowptr, cursor, colarr);

  // ---- casts ----
  k_cast8<<<(int)(NNH / 8 + 255) / 256, 256, 0, stream>>>(x, bufA, (int)(NNH / 8));
  k_prep_w<<<(7 * 16384 + CC * 128 + 255) / 256, 256, 0, stream>>>(
      pw1, pw2, swl, swr, cw1, cw2, wt);

  const int MG = (NN + 63) / 64;  // 782
  // t1 = relu(x @ pw1 + pb1)            -> bufB (bf16)
  k_mfma<HH, POST_RELU, false, true><<<MG, 256, 0, stream>>>(
      bufA, wt + 0 * 16384, pb1, nullptr, nullptr, nullptr, nullptr, nullptr, bufB);
  // h = LN(t1 @ pw2 + pb2)              -> h (f32) + hb (bf16)
  k_mfma<HH, POST_LN, true, true><<<MG, 256, 0, stream>>>(
      bufB, wt + 1 * 16384, pb2, nullptr, nullptr, ing, inb, h, hb);

  for (int l = 0; l < 2; ++l) {
    // agg = mean in-neighbors(hb)       -> bufA (bf16)
    k_gather_bf<<<(NN + 3) / 4, 256, 0, stream>>>(hb, rowptr, colarr, inv, bufA);
    // tmp = agg @ wl + bl               -> tmp (f32)
    k_mfma<HH, POST_NONE, true, false><<<MG, 256, 0, stream>>>(
        bufA, wt + (size_t)(2 + l) * 16384, sbl + (size_t)l * HH,
        nullptr, nullptr, nullptr, nullptr, tmp, nullptr);
    // h' = LN(h + relu(tmp + h @ wr))   -> h/out_h (f32) + hb (bf16, in-place safe)
    k_mfma<HH, POST_COMBINE, true, true><<<MG, 256, 0, stream>>>(
        hb, wt + (size_t)(4 + l) * 16384, nullptr, tmp, h,
        lng + (size_t)l * HH, lnb + (size_t)l * HH,
        (l == 0) ? h : out_h, hb);
  }

  // t3 = relu(h @ cw1 + cb1)            -> bufA (bf16)
  k_mfma<HH, POST_RELU, false, true><<<MG, 256, 0, stream>>>(
      hb, wt + 6 * 16384, cb1, nullptr, nullptr, nullptr, nullptr, nullptr, bufA);
  // logits = t3 @ cw2 + cb2             -> out_logits (f32)
  k_mfma<CC, POST_NONE, true, false><<<MG, 256, 0, stream>>>(
      bufA, wt + 7 * 16384, cb2, nullptr, nullptr, nullptr, nullptr, out_logits, nullptr);
}

// Round 4
// 326.041 us; speedup vs baseline: 2.8771x; 1.0925x over previous
//
#include <hip/hip_runtime.h>

// GNN encoder: input MLP + LN, 2x SAGEConv(mean) + ReLU + residual + LN, classifier MLP.
// Round 4:
//  - gather: 4 edges/iter (quarter-wave ushort8) for 2x MLP
//  - k_sage: fused agg@wl + h@wr + bias + relu + residual(bf16) + LN (tmp/f32-h eliminated)
//  - all MFMA kernels: 2 row-tiles per wave (B-frag reuse x2)
//  - first matmul converts f32 x on the fly (cast kernel gone)
//  - classifier fused (t3 via per-wave LDS tile, stride 136)
//  - CSR: memset + degree + single-block scan(+invcnt) + fill

namespace {

constexpr int NN = 50000;
constexpr int EE = 640000;
constexpr int HH = 128;
constexpr int CC = 40;

constexpr int POST_RELU = 1, POST_LN = 2;

typedef unsigned short u16;
typedef __attribute__((ext_vector_type(8))) short s16x8;
typedef __attribute__((ext_vector_type(8))) unsigned short u16x8;
typedef __attribute__((ext_vector_type(4))) float f32x4;

__device__ __forceinline__ float b2f(u16 h) {
  unsigned int u = ((unsigned int)h) << 16;
  return __builtin_bit_cast(float, u);
}
__device__ __forceinline__ u16 f2b(float f) {
  unsigned int u = __builtin_bit_cast(unsigned int, f);
  u += 0x7FFFu + ((u >> 16) & 1u);
  return (u16)(u >> 16);
}

// ---------------- CSR build ----------------
__global__ void k_degree(const int* __restrict__ ei, int* __restrict__ cnt) {
  int e = blockIdx.x * 256 + threadIdx.x;
  if (e < EE) atomicAdd(&cnt[ei[EE + e]], 1);
}

// single-block exclusive scan over cnt[NN] -> rowptr, plus inv = 1/cnt
constexpr int SCH = (NN + 1023) / 1024;  // 49
__global__ __launch_bounds__(1024) void k_scan(const int* __restrict__ cnt,
                                               int* __restrict__ rowptr,
                                               float* __restrict__ inv) {
  __shared__ int ps[1024];
  const int t = threadIdx.x;
  const int i0 = t * SCH;
  int local[SCH];
  int s = 0;
#pragma unroll
  for (int k = 0; k < SCH; ++k) {
    const int i = i0 + k;
    const int v = i < NN ? cnt[i] : 0;
    local[k] = v;
    s += v;
  }
  ps[t] = s;
  __syncthreads();
  for (int off = 1; off < 1024; off <<= 1) {
    const int add = t >= off ? ps[t - off] : 0;
    __syncthreads();
    ps[t] += add;
    __syncthreads();
  }
  int ex = ps[t] - s;
#pragma unroll
  for (int k = 0; k < SCH; ++k) {
    const int i = i0 + k;
    if (i < NN) {
      rowptr[i] = ex;
      inv[i] = local[k] > 0 ? 1.0f / (float)local[k] : 0.0f;
      ex += local[k];
    }
  }
  if (t == 0) rowptr[NN] = EE;
}

__global__ void k_fill(const int* __restrict__ ei, const int* __restrict__ rowptr,
                       int* __restrict__ cursor, int* __restrict__ col) {
  int e = blockIdx.x * 256 + threadIdx.x;
  if (e >= EE) return;
  int s = ei[e];
  int d = ei[EE + e];
  int pos = atomicAdd(&cursor[d], 1);
  col[rowptr[d] + pos] = s;
}

// transpose+cast all weights into wt slots {pw1,pw2,wl0,wl1,wr0,wr1,cw1,cw2T}
__global__ void k_prep_w(const float* __restrict__ pw1, const float* __restrict__ pw2,
                         const float* __restrict__ swl, const float* __restrict__ swr,
                         const float* __restrict__ cw1, const float* __restrict__ cw2,
                         u16* __restrict__ wt) {
  int flat = blockIdx.x * 256 + threadIdx.x;
  const int SEVEN = 7 * 16384;
  if (flat < SEVEN) {
    int id = flat >> 14;
    int off = flat & 16383;
    int n = off >> 7, k = off & 127;
    const float* s;
    switch (id) {
      case 0: s = pw1; break;
      case 1: s = pw2; break;
      case 2: s = swl; break;
      case 3: s = swl + 16384; break;
      case 4: s = swr; break;
      case 5: s = swr + 16384; break;
      default: s = cw1; break;
    }
    wt[(size_t)id * 16384 + n * 128 + k] = f2b(s[k * 128 + n]);
  } else {
    int off = flat - SEVEN;
    if (off < CC * 128) {
      int n = off >> 7, k = off & 127;
      wt[(size_t)7 * 16384 + n * 128 + k] = f2b(cw2[k * CC + n]);
    }
  }
}

// ---------------- aggregation: wave per node, 4 edges per iter ----------------
__global__ __launch_bounds__(256) void k_gather4(
    const u16* __restrict__ hb, const int* __restrict__ rowptr,
    const int* __restrict__ col, const float* __restrict__ inv,
    u16* __restrict__ agg) {
  const int tid = threadIdx.x;
  const int wv = tid >> 6, ln = tid & 63;
  const int node = blockIdx.x * 4 + wv;
  if (node >= NN) return;
  const int start = rowptr[node];
  const int end = rowptr[node + 1];
  const int quarter = ln >> 4;
  const int cl = (ln & 15) * 8;
  float a[8] = {0.f, 0.f, 0.f, 0.f, 0.f, 0.f, 0.f, 0.f};
  int i = start;
  for (; i + 4 <= end; i += 4) {
    const int s = col[i + quarter];
    const u16x8 v = *reinterpret_cast<const u16x8*>(&hb[(size_t)s * HH + cl]);
#pragma unroll
    for (int k = 0; k < 8; ++k) a[k] += b2f(v[k]);
  }
  if (i < end && quarter < end - i) {
    const int s = col[i + quarter];
    const u16x8 v = *reinterpret_cast<const u16x8*>(&hb[(size_t)s * HH + cl]);
#pragma unroll
    for (int k = 0; k < 8; ++k) a[k] += b2f(v[k]);
  }
#pragma unroll
  for (int k = 0; k < 8; ++k) {
    a[k] += __shfl_xor(a[k], 16);
    a[k] += __shfl_xor(a[k], 32);
  }
  if (quarter == 0) {
    const float sc = inv[node];
    u16x8 o;
#pragma unroll
    for (int k = 0; k < 8; ++k) o[k] = f2b(a[k] * sc);
    *reinterpret_cast<u16x8*>(&agg[(size_t)node * HH + cl]) = o;
  }
}

// ---------------- input-MLP matmuls: 2 row-tiles/wave, fused epilogue ----------------
// out = post( A[N,128] @ WT^T + bias );  SRCF32: A is f32 (converted on the fly)
template <int POST, bool SRCF32>
__global__ __launch_bounds__(256) void k_in(
    const u16* __restrict__ A, const float* __restrict__ Af,
    const u16* __restrict__ WT, const float* __restrict__ bias,
    const float* __restrict__ lg, const float* __restrict__ lb,
    u16* __restrict__ outb) {
  const int tid = threadIdx.x;
  const int wv = tid >> 6, ln = tid & 63;
  const int lrow = ln & 15, kg = ln >> 4;
  const int tbase = blockIdx.x * 128 + wv * 32;
  const int ar0 = min(tbase + lrow, NN - 1);
  const int ar1 = min(tbase + 16 + lrow, NN - 1);

  f32x4 acc0[8], acc1[8];
#pragma unroll
  for (int cf = 0; cf < 8; ++cf) {
    acc0[cf] = (f32x4){0.f, 0.f, 0.f, 0.f};
    acc1[cf] = (f32x4){0.f, 0.f, 0.f, 0.f};
  }

#pragma unroll
  for (int ks = 0; ks < 4; ++ks) {
    s16x8 a0, a1;
    if constexpr (SRCF32) {
      const float4* p0 = reinterpret_cast<const float4*>(Af + (size_t)ar0 * 128 + ks * 32 + kg * 8);
      const float4* p1 = reinterpret_cast<const float4*>(Af + (size_t)ar1 * 128 + ks * 32 + kg * 8);
      float4 x0 = p0[0], x1 = p0[1], y0 = p1[0], y1 = p1[1];
      a0[0] = (short)f2b(x0.x); a0[1] = (short)f2b(x0.y); a0[2] = (short)f2b(x0.z); a0[3] = (short)f2b(x0.w);
      a0[4] = (short)f2b(x1.x); a0[5] = (short)f2b(x1.y); a0[6] = (short)f2b(x1.z); a0[7] = (short)f2b(x1.w);
      a1[0] = (short)f2b(y0.x); a1[1] = (short)f2b(y0.y); a1[2] = (short)f2b(y0.z); a1[3] = (short)f2b(y0.w);
      a1[4] = (short)f2b(y1.x); a1[5] = (short)f2b(y1.y); a1[6] = (short)f2b(y1.z); a1[7] = (short)f2b(y1.w);
    } else {
      a0 = *reinterpret_cast<const s16x8*>(A + (size_t)ar0 * 128 + ks * 32 + kg * 8);
      a1 = *reinterpret_cast<const s16x8*>(A + (size_t)ar1 * 128 + ks * 32 + kg * 8);
    }
#pragma unroll
    for (int cf = 0; cf < 8; ++cf) {
      const s16x8 bf = *reinterpret_cast<const s16x8*>(WT + (size_t)(cf * 16 + lrow) * 128 + ks * 32 + kg * 8);
      acc0[cf] = __builtin_amdgcn_mfma_f32_16x16x32_bf16(a0, bf, acc0[cf], 0, 0, 0);
      acc1[cf] = __builtin_amdgcn_mfma_f32_16x16x32_bf16(a1, bf, acc1[cf], 0, 0, 0);
    }
  }

  float bb[8], gm[8], gb[8];
#pragma unroll
  for (int cf = 0; cf < 8; ++cf) {
    const int c = cf * 16 + lrow;
    bb[cf] = bias[c];
    if constexpr (POST == POST_LN) { gm[cf] = lg[c]; gb[cf] = lb[c]; }
  }

#pragma unroll
  for (int t = 0; t < 2; ++t) {
    const int base = tbase + t * 16;
#pragma unroll
    for (int j = 0; j < 4; ++j) {
      const int r = base + kg * 4 + j;
      float v[8];
#pragma unroll
      for (int cf = 0; cf < 8; ++cf) v[cf] = (t ? acc1[cf][j] : acc0[cf][j]) + bb[cf];
      if constexpr (POST == POST_RELU) {
#pragma unroll
        for (int cf = 0; cf < 8; ++cf) v[cf] = fmaxf(v[cf], 0.0f);
      }
      if constexpr (POST == POST_LN) {
        float s = 0.f;
#pragma unroll
        for (int cf = 0; cf < 8; ++cf) s += v[cf];
        s += __shfl_xor(s, 1); s += __shfl_xor(s, 2);
        s += __shfl_xor(s, 4); s += __shfl_xor(s, 8);
        const float mu = s * (1.0f / 128);
        float q = 0.f;
#pragma unroll
        for (int cf = 0; cf < 8; ++cf) { const float d = v[cf] - mu; q += d * d; }
        q += __shfl_xor(q, 1); q += __shfl_xor(q, 2);
        q += __shfl_xor(q, 4); q += __shfl_xor(q, 8);
        const float istd = rsqrtf(q * (1.0f / 128) + 1e-5f);
#pragma unroll
        for (int cf = 0; cf < 8; ++cf) v[cf] = (v[cf] - mu) * istd * gm[cf] + gb[cf];
      }
      if (r < NN) {
#pragma unroll
        for (int cf = 0; cf < 8; ++cf) outb[(size_t)r * 128 + cf * 16 + lrow] = f2b(v[cf]);
      }
    }
  }
}

// ---------------- fused SAGE layer ----------------
// h' = LN( h + relu(agg@WL + bl + h@WR) ); resid read from bf16 hb (in-place safe)
template <bool LAST>
__global__ __launch_bounds__(256) void k_sage(
    const u16* __restrict__ agg, const u16* __restrict__ hb,
    const u16* __restrict__ WTl, const u16* __restrict__ WTr,
    const float* __restrict__ bl, const float* __restrict__ lg,
    const float* __restrict__ lb, u16* __restrict__ hb_out,
    float* __restrict__ outf) {
  const int tid = threadIdx.x;
  const int wv = tid >> 6, ln = tid & 63;
  const int lrow = ln & 15, kg = ln >> 4;
  const int tbase = blockIdx.x * 128 + wv * 32;
  const int ar0 = min(tbase + lrow, NN - 1);
  const int ar1 = min(tbase + 16 + lrow, NN - 1);

  f32x4 acc0[8], acc1[8];
#pragma unroll
  for (int cf = 0; cf < 8; ++cf) {
    acc0[cf] = (f32x4){0.f, 0.f, 0.f, 0.f};
    acc1[cf] = (f32x4){0.f, 0.f, 0.f, 0.f};
  }

#pragma unroll
  for (int ks = 0; ks < 4; ++ks) {
    const s16x8 g0 = *reinterpret_cast<const s16x8*>(agg + (size_t)ar0 * 128 + ks * 32 + kg * 8);
    const s16x8 g1 = *reinterpret_cast<const s16x8*>(agg + (size_t)ar1 * 128 + ks * 32 + kg * 8);
    const s16x8 h0 = *reinterpret_cast<const s16x8*>(hb + (size_t)ar0 * 128 + ks * 32 + kg * 8);
    const s16x8 h1 = *reinterpret_cast<const s16x8*>(hb + (size_t)ar1 * 128 + ks * 32 + kg * 8);
#pragma unroll
    for (int cf = 0; cf < 8; ++cf) {
      const s16x8 bwl = *reinterpret_cast<const s16x8*>(WTl + (size_t)(cf * 16 + lrow) * 128 + ks * 32 + kg * 8);
      const s16x8 bwr = *reinterpret_cast<const s16x8*>(WTr + (size_t)(cf * 16 + lrow) * 128 + ks * 32 + kg * 8);
      acc0[cf] = __builtin_amdgcn_mfma_f32_16x16x32_bf16(g0, bwl, acc0[cf], 0, 0, 0);
      acc0[cf] = __builtin_amdgcn_mfma_f32_16x16x32_bf16(h0, bwr, acc0[cf], 0, 0, 0);
      acc1[cf] = __builtin_amdgcn_mfma_f32_16x16x32_bf16(g1, bwl, acc1[cf], 0, 0, 0);
      acc1[cf] = __builtin_amdgcn_mfma_f32_16x16x32_bf16(h1, bwr, acc1[cf], 0, 0, 0);
    }
  }

  float bb[8], gm[8], gb[8];
#pragma unroll
  for (int cf = 0; cf < 8; ++cf) {
    const int c = cf * 16 + lrow;
    bb[cf] = bl[c];
    gm[cf] = lg[c];
    gb[cf] = lb[c];
  }

#pragma unroll
  for (int t = 0; t < 2; ++t) {
    const int base = tbase + t * 16;
#pragma unroll
    for (int j = 0; j < 4; ++j) {
      const int r = base + kg * 4 + j;
      const int rs = r < NN ? r : NN - 1;
      float v[8];
#pragma unroll
      for (int cf = 0; cf < 8; ++cf) {
        const int c = cf * 16 + lrow;
        const float rd = b2f(hb[(size_t)rs * 128 + c]);
        v[cf] = rd + fmaxf((t ? acc1[cf][j] : acc0[cf][j]) + bb[cf], 0.0f);
      }
      float s = 0.f;
#pragma unroll
      for (int cf = 0; cf < 8; ++cf) s += v[cf];
      s += __shfl_xor(s, 1); s += __shfl_xor(s, 2);
      s += __shfl_xor(s, 4); s += __shfl_xor(s, 8);
      const float mu = s * (1.0f / 128);
      float q = 0.f;
#pragma unroll
      for (int cf = 0; cf < 8; ++cf) { const float d = v[cf] - mu; q += d * d; }
      q += __shfl_xor(q, 1); q += __shfl_xor(q, 2);
      q += __shfl_xor(q, 4); q += __shfl_xor(q, 8);
      const float istd = rsqrtf(q * (1.0f / 128) + 1e-5f);
      if (r < NN) {
#pragma unroll
        for (int cf = 0; cf < 8; ++cf) {
          const int c = cf * 16 + lrow;
          const float o = (v[cf] - mu) * istd * gm[cf] + gb[cf];
          hb_out[(size_t)r * 128 + c] = f2b(o);
          if constexpr (LAST) outf[(size_t)r * 128 + c] = o;
        }
      }
    }
  }
}

// ---------------- fused classifier ----------------
// logits = relu(h@cw1 + cb1) @ cw2 + cb2 ; t3 tile round-trips per-wave LDS
__global__ __launch_bounds__(256) void k_cls(
    const u16* __restrict__ hb, const u16* __restrict__ WT1,
    const float* __restrict__ cb1, const u16* __restrict__ WT2,
    const float* __restrict__ cb2, float* __restrict__ logits) {
  __shared__ u16 t3[4][16][136];
  const int tid = threadIdx.x;
  const int wv = tid >> 6, ln = tid & 63;
  const int lrow = ln & 15, kg = ln >> 4;
  const int row0 = blockIdx.x * 64 + wv * 16;
  const int ar = min(row0 + lrow, NN - 1);

  f32x4 acc[8];
#pragma unroll
  for (int cf = 0; cf < 8; ++cf) acc[cf] = (f32x4){0.f, 0.f, 0.f, 0.f};
#pragma unroll
  for (int ks = 0; ks < 4; ++ks) {
    const s16x8 a = *reinterpret_cast<const s16x8*>(hb + (size_t)ar * 128 + ks * 32 + kg * 8);
#pragma unroll
    for (int cf = 0; cf < 8; ++cf) {
      const s16x8 bf = *reinterpret_cast<const s16x8*>(WT1 + (size_t)(cf * 16 + lrow) * 128 + ks * 32 + kg * 8);
      acc[cf] = __builtin_amdgcn_mfma_f32_16x16x32_bf16(a, bf, acc[cf], 0, 0, 0);
    }
  }
  float bb[8];
#pragma unroll
  for (int cf = 0; cf < 8; ++cf) bb[cf] = cb1[cf * 16 + lrow];
#pragma unroll
  for (int j = 0; j < 4; ++j) {
#pragma unroll
    for (int cf = 0; cf < 8; ++cf)
      t3[wv][kg * 4 + j][cf * 16 + lrow] = f2b(fmaxf(acc[cf][j] + bb[cf], 0.0f));
  }

  // phase 2: t3 tile (this wave's own LDS region) @ cw2T
  f32x4 acc2[3];
#pragma unroll
  for (int cf = 0; cf < 3; ++cf) acc2[cf] = (f32x4){0.f, 0.f, 0.f, 0.f};
#pragma unroll
  for (int ks = 0; ks < 4; ++ks) {
    const s16x8 a = *reinterpret_cast<const s16x8*>(&t3[wv][lrow][ks * 32 + kg * 8]);
#pragma unroll
    for (int cf = 0; cf < 3; ++cf) {
      const int bn = min(cf * 16 + lrow, CC - 1);
      const s16x8 bf = *reinterpret_cast<const s16x8*>(WT2 + (size_t)bn * 128 + ks * 32 + kg * 8);
      acc2[cf] = __builtin_amdgcn_mfma_f32_16x16x32_bf16(a, bf, acc2[cf], 0, 0, 0);
    }
  }
#pragma unroll
  for (int j = 0; j < 4; ++j) {
    const int r = row0 + kg * 4 + j;
    if (r < NN) {
#pragma unroll
      for (int cf = 0; cf < 3; ++cf) {
        const int c = cf * 16 + lrow;
        if (c < CC) logits[(size_t)r * CC + c] = acc2[cf][j] + cb2[c];
      }
    }
  }
}

}  // namespace

extern "C" void kernel_launch(void* const* d_in, const int* in_sizes, int n_in,
                              void* d_out, int out_size, void* d_ws, size_t ws_size,
                              hipStream_t stream) {
  (void)in_sizes; (void)n_in; (void)out_size; (void)ws_size;
  const float* x   = (const float*)d_in[0];
  const int*   ei  = (const int*)d_in[1];
  const float* pw1 = (const float*)d_in[2];
  const float* pb1 = (const float*)d_in[3];
  const float* pw2 = (const float*)d_in[4];
  const float* pb2 = (const float*)d_in[5];
  const float* ing = (const float*)d_in[6];
  const float* inb = (const float*)d_in[7];
  const float* swl = (const float*)d_in[8];
  const float* sbl = (const float*)d_in[9];
  const float* swr = (const float*)d_in[10];
  const float* lng = (const float*)d_in[11];
  const float* lnb = (const float*)d_in[12];
  const float* cw1 = (const float*)d_in[13];
  const float* cb1 = (const float*)d_in[14];
  const float* cw2 = (const float*)d_in[15];
  const float* cb2 = (const float*)d_in[16];

  float* out_logits = (float*)d_out;
  float* out_h = out_logits + (size_t)NN * CC;

  const size_t NNH = (size_t)NN * HH;
  u16*   hb   = (u16*)d_ws;                // 12.8 MB
  u16*   bufA = hb + NNH;                  // 12.8 MB (t1 / agg)
  u16*   wt   = bufA + NNH;                // 256 KB
  int*   cnt    = (int*)(wt + 8 * 16384);  // NN
  int*   cursor = cnt + NN;                // NN (adjacent: single memset)
  float* inv    = (float*)(cursor + NN);   // NN
  int*   rowptr = (int*)(inv + NN);        // NN+1
  int*   colarr = rowptr + NN + 1;         // EE

  // ---- CSR build ----
  hipMemsetAsync(cnt, 0, 2 * NN * sizeof(int), stream);
  k_degree<<<(EE + 255) / 256, 256, 0, stream>>>(ei, cnt);
  k_scan<<<1, 1024, 0, stream>>>(cnt, rowptr, inv);
  k_fill<<<(EE + 255) / 256, 256, 0, stream>>>(ei, rowptr, cursor, colarr);
  k_prep_w<<<(7 * 16384 + CC * 128 + 255) / 256, 256, 0, stream>>>(
      pw1, pw2, swl, swr, cw1, cw2, wt);

  const int MG = (NN + 127) / 128;  // 391
  // t1 = relu(x @ pw1 + pb1)           -> bufA (bf16), x converted on the fly
  k_in<POST_RELU, true><<<MG, 256, 0, stream>>>(
      nullptr, x, wt + 0 * 16384, pb1, nullptr, nullptr, bufA);
  // h = LN(t1 @ pw2 + pb2)             -> hb
  k_in<POST_LN, false><<<MG, 256, 0, stream>>>(
      bufA, nullptr, wt + 1 * 16384, pb2, ing, inb, hb);

  // layer 0
  k_gather4<<<(NN + 3) / 4, 256, 0, stream>>>(hb, rowptr, colarr, inv, bufA);
  k_sage<false><<<MG, 256, 0, stream>>>(
      bufA, hb, wt + 2 * 16384, wt + 4 * 16384, sbl, lng, lnb, hb, nullptr);
  // layer 1
  k_gather4<<<(NN + 3) / 4, 256, 0, stream>>>(hb, rowptr, colarr, inv, bufA);
  k_sage<true><<<MG, 256, 0, stream>>>(
      bufA, hb, wt + 3 * 16384, wt + 5 * 16384, sbl + HH, lng + HH, lnb + HH, hb, out_h);

  // classifier (fused)
  k_cls<<<(NN + 63) / 64, 256, 0, stream>>>(
      hb, wt + 6 * 16384, cb1, wt + 7 * 16384, cb2, out_logits);
}

// Round 5
// 256.863 us; speedup vs baseline: 3.6519x; 1.2693x over previous
//
#include <hip/hip_runtime.h>

// GNN encoder: input MLP + LN, 2x SAGEConv(mean) + ReLU + residual + LN, classifier MLP.
// Round 5: revert single-block scan (81us serialized on 1 CU!) to multi-block
// 3-kernel hierarchical scan with inv fused into phase 1. Everything else as round 4:
//  - gather: 4 edges/iter (quarter-wave ushort8)
//  - k_sage: fused agg@wl + h@wr + bias + relu + residual(bf16) + LN
//  - MFMA kernels: 2 row-tiles/wave, bf16 inputs, f32 accum, zero LDS
//  - first matmul converts f32 x on the fly; classifier fused via per-wave LDS tile

namespace {

constexpr int NN = 50000;
constexpr int EE = 640000;
constexpr int HH = 128;
constexpr int CC = 40;
constexpr int SCAN_NB = (NN + 255) / 256;  // 196

constexpr int POST_RELU = 1, POST_LN = 2;

typedef unsigned short u16;
typedef __attribute__((ext_vector_type(8))) short s16x8;
typedef __attribute__((ext_vector_type(8))) unsigned short u16x8;
typedef __attribute__((ext_vector_type(4))) float f32x4;

__device__ __forceinline__ float b2f(u16 h) {
  unsigned int u = ((unsigned int)h) << 16;
  return __builtin_bit_cast(float, u);
}
__device__ __forceinline__ u16 f2b(float f) {
  unsigned int u = __builtin_bit_cast(unsigned int, f);
  u += 0x7FFFu + ((u >> 16) & 1u);
  return (u16)(u >> 16);
}

// ---------------- CSR build ----------------
__global__ void k_degree(const int* __restrict__ ei, int* __restrict__ cnt) {
  int e = blockIdx.x * 256 + threadIdx.x;
  if (e < EE) atomicAdd(&cnt[ei[EE + e]], 1);
}

// phase 1: per-block exclusive scan + block sums + inv = 1/cnt
__global__ void k_scan_block(const int* __restrict__ cnt, int* __restrict__ rowptr,
                             int* __restrict__ bsum, float* __restrict__ inv) {
  __shared__ int s[256];
  const int t = threadIdx.x;
  const int i = blockIdx.x * 256 + t;
  const int v = i < NN ? cnt[i] : 0;
  s[t] = v;
  __syncthreads();
  for (int off = 1; off < 256; off <<= 1) {
    int add = t >= off ? s[t - off] : 0;
    __syncthreads();
    s[t] += add;
    __syncthreads();
  }
  if (i < NN) {
    rowptr[i] = s[t] - v;  // exclusive within block
    inv[i] = v > 0 ? 1.0f / (float)v : 0.0f;
  }
  if (t == 255) bsum[blockIdx.x] = s[255];
}

// phase 2: scan the 196 block sums
__global__ void k_scan_tops(int* __restrict__ bsum) {
  __shared__ int s[256];
  const int t = threadIdx.x;
  const int v = t < SCAN_NB ? bsum[t] : 0;
  s[t] = v;
  __syncthreads();
  for (int off = 1; off < 256; off <<= 1) {
    int add = t >= off ? s[t - off] : 0;
    __syncthreads();
    s[t] += add;
    __syncthreads();
  }
  if (t < SCAN_NB) bsum[t] = s[t] - v;
}

// phase 3: add block offsets
__global__ void k_scan_add(int* __restrict__ rowptr, const int* __restrict__ bsum) {
  const int i = blockIdx.x * 256 + threadIdx.x;
  if (i < NN) rowptr[i] += bsum[blockIdx.x];
  if (i == 0) rowptr[NN] = EE;
}

__global__ void k_fill(const int* __restrict__ ei, const int* __restrict__ rowptr,
                       int* __restrict__ cursor, int* __restrict__ col) {
  int e = blockIdx.x * 256 + threadIdx.x;
  if (e >= EE) return;
  int s = ei[e];
  int d = ei[EE + e];
  int pos = atomicAdd(&cursor[d], 1);
  col[rowptr[d] + pos] = s;
}

// transpose+cast all weights into wt slots {pw1,pw2,wl0,wl1,wr0,wr1,cw1,cw2T}
__global__ void k_prep_w(const float* __restrict__ pw1, const float* __restrict__ pw2,
                         const float* __restrict__ swl, const float* __restrict__ swr,
                         const float* __restrict__ cw1, const float* __restrict__ cw2,
                         u16* __restrict__ wt) {
  int flat = blockIdx.x * 256 + threadIdx.x;
  const int SEVEN = 7 * 16384;
  if (flat < SEVEN) {
    int id = flat >> 14;
    int off = flat & 16383;
    int n = off >> 7, k = off & 127;
    const float* s;
    switch (id) {
      case 0: s = pw1; break;
      case 1: s = pw2; break;
      case 2: s = swl; break;
      case 3: s = swl + 16384; break;
      case 4: s = swr; break;
      case 5: s = swr + 16384; break;
      default: s = cw1; break;
    }
    wt[(size_t)id * 16384 + n * 128 + k] = f2b(s[k * 128 + n]);
  } else {
    int off = flat - SEVEN;
    if (off < CC * 128) {
      int n = off >> 7, k = off & 127;
      wt[(size_t)7 * 16384 + n * 128 + k] = f2b(cw2[k * CC + n]);
    }
  }
}

// ---------------- aggregation: wave per node, 4 edges per iter ----------------
__global__ __launch_bounds__(256) void k_gather4(
    const u16* __restrict__ hb, const int* __restrict__ rowptr,
    const int* __restrict__ col, const float* __restrict__ inv,
    u16* __restrict__ agg) {
  const int tid = threadIdx.x;
  const int wv = tid >> 6, ln = tid & 63;
  const int node = blockIdx.x * 4 + wv;
  if (node >= NN) return;
  const int start = rowptr[node];
  const int end = rowptr[node + 1];
  const int quarter = ln >> 4;
  const int cl = (ln & 15) * 8;
  float a[8] = {0.f, 0.f, 0.f, 0.f, 0.f, 0.f, 0.f, 0.f};
  int i = start;
  for (; i + 4 <= end; i += 4) {
    const int s = col[i + quarter];
    const u16x8 v = *reinterpret_cast<const u16x8*>(&hb[(size_t)s * HH + cl]);
#pragma unroll
    for (int k = 0; k < 8; ++k) a[k] += b2f(v[k]);
  }
  if (i < end && quarter < end - i) {
    const int s = col[i + quarter];
    const u16x8 v = *reinterpret_cast<const u16x8*>(&hb[(size_t)s * HH + cl]);
#pragma unroll
    for (int k = 0; k < 8; ++k) a[k] += b2f(v[k]);
  }
#pragma unroll
  for (int k = 0; k < 8; ++k) {
    a[k] += __shfl_xor(a[k], 16);
    a[k] += __shfl_xor(a[k], 32);
  }
  if (quarter == 0) {
    const float sc = inv[node];
    u16x8 o;
#pragma unroll
    for (int k = 0; k < 8; ++k) o[k] = f2b(a[k] * sc);
    *reinterpret_cast<u16x8*>(&agg[(size_t)node * HH + cl]) = o;
  }
}

// ---------------- input-MLP matmuls: 2 row-tiles/wave, fused epilogue ----------------
template <int POST, bool SRCF32>
__global__ __launch_bounds__(256) void k_in(
    const u16* __restrict__ A, const float* __restrict__ Af,
    const u16* __restrict__ WT, const float* __restrict__ bias,
    const float* __restrict__ lg, const float* __restrict__ lb,
    u16* __restrict__ outb) {
  const int tid = threadIdx.x;
  const int wv = tid >> 6, ln = tid & 63;
  const int lrow = ln & 15, kg = ln >> 4;
  const int tbase = blockIdx.x * 128 + wv * 32;
  const int ar0 = min(tbase + lrow, NN - 1);
  const int ar1 = min(tbase + 16 + lrow, NN - 1);

  f32x4 acc0[8], acc1[8];
#pragma unroll
  for (int cf = 0; cf < 8; ++cf) {
    acc0[cf] = (f32x4){0.f, 0.f, 0.f, 0.f};
    acc1[cf] = (f32x4){0.f, 0.f, 0.f, 0.f};
  }

#pragma unroll
  for (int ks = 0; ks < 4; ++ks) {
    s16x8 a0, a1;
    if constexpr (SRCF32) {
      const float4* p0 = reinterpret_cast<const float4*>(Af + (size_t)ar0 * 128 + ks * 32 + kg * 8);
      const float4* p1 = reinterpret_cast<const float4*>(Af + (size_t)ar1 * 128 + ks * 32 + kg * 8);
      float4 x0 = p0[0], x1 = p0[1], y0 = p1[0], y1 = p1[1];
      a0[0] = (short)f2b(x0.x); a0[1] = (short)f2b(x0.y); a0[2] = (short)f2b(x0.z); a0[3] = (short)f2b(x0.w);
      a0[4] = (short)f2b(x1.x); a0[5] = (short)f2b(x1.y); a0[6] = (short)f2b(x1.z); a0[7] = (short)f2b(x1.w);
      a1[0] = (short)f2b(y0.x); a1[1] = (short)f2b(y0.y); a1[2] = (short)f2b(y0.z); a1[3] = (short)f2b(y0.w);
      a1[4] = (short)f2b(y1.x); a1[5] = (short)f2b(y1.y); a1[6] = (short)f2b(y1.z); a1[7] = (short)f2b(y1.w);
    } else {
      a0 = *reinterpret_cast<const s16x8*>(A + (size_t)ar0 * 128 + ks * 32 + kg * 8);
      a1 = *reinterpret_cast<const s16x8*>(A + (size_t)ar1 * 128 + ks * 32 + kg * 8);
    }
#pragma unroll
    for (int cf = 0; cf < 8; ++cf) {
      const s16x8 bf = *reinterpret_cast<const s16x8*>(WT + (size_t)(cf * 16 + lrow) * 128 + ks * 32 + kg * 8);
      acc0[cf] = __builtin_amdgcn_mfma_f32_16x16x32_bf16(a0, bf, acc0[cf], 0, 0, 0);
      acc1[cf] = __builtin_amdgcn_mfma_f32_16x16x32_bf16(a1, bf, acc1[cf], 0, 0, 0);
    }
  }

  float bb[8], gm[8], gb[8];
#pragma unroll
  for (int cf = 0; cf < 8; ++cf) {
    const int c = cf * 16 + lrow;
    bb[cf] = bias[c];
    if constexpr (POST == POST_LN) { gm[cf] = lg[c]; gb[cf] = lb[c]; }
  }

#pragma unroll
  for (int t = 0; t < 2; ++t) {
    const int base = tbase + t * 16;
#pragma unroll
    for (int j = 0; j < 4; ++j) {
      const int r = base + kg * 4 + j;
      float v[8];
#pragma unroll
      for (int cf = 0; cf < 8; ++cf) v[cf] = (t ? acc1[cf][j] : acc0[cf][j]) + bb[cf];
      if constexpr (POST == POST_RELU) {
#pragma unroll
        for (int cf = 0; cf < 8; ++cf) v[cf] = fmaxf(v[cf], 0.0f);
      }
      if constexpr (POST == POST_LN) {
        float s = 0.f;
#pragma unroll
        for (int cf = 0; cf < 8; ++cf) s += v[cf];
        s += __shfl_xor(s, 1); s += __shfl_xor(s, 2);
        s += __shfl_xor(s, 4); s += __shfl_xor(s, 8);
        const float mu = s * (1.0f / 128);
        float q = 0.f;
#pragma unroll
        for (int cf = 0; cf < 8; ++cf) { const float d = v[cf] - mu; q += d * d; }
        q += __shfl_xor(q, 1); q += __shfl_xor(q, 2);
        q += __shfl_xor(q, 4); q += __shfl_xor(q, 8);
        const float istd = rsqrtf(q * (1.0f / 128) + 1e-5f);
#pragma unroll
        for (int cf = 0; cf < 8; ++cf) v[cf] = (v[cf] - mu) * istd * gm[cf] + gb[cf];
      }
      if (r < NN) {
#pragma unroll
        for (int cf = 0; cf < 8; ++cf) outb[(size_t)r * 128 + cf * 16 + lrow] = f2b(v[cf]);
      }
    }
  }
}

// ---------------- fused SAGE layer ----------------
template <bool LAST>
__global__ __launch_bounds__(256) void k_sage(
    const u16* __restrict__ agg, const u16* __restrict__ hb,
    const u16* __restrict__ WTl, const u16* __restrict__ WTr,
    const float* __restrict__ bl, const float* __restrict__ lg,
    const float* __restrict__ lb, u16* __restrict__ hb_out,
    float* __restrict__ outf) {
  const int tid = threadIdx.x;
  const int wv = tid >> 6, ln = tid & 63;
  const int lrow = ln & 15, kg = ln >> 4;
  const int tbase = blockIdx.x * 128 + wv * 32;
  const int ar0 = min(tbase + lrow, NN - 1);
  const int ar1 = min(tbase + 16 + lrow, NN - 1);

  f32x4 acc0[8], acc1[8];
#pragma unroll
  for (int cf = 0; cf < 8; ++cf) {
    acc0[cf] = (f32x4){0.f, 0.f, 0.f, 0.f};
    acc1[cf] = (f32x4){0.f, 0.f, 0.f, 0.f};
  }

#pragma unroll
  for (int ks = 0; ks < 4; ++ks) {
    const s16x8 g0 = *reinterpret_cast<const s16x8*>(agg + (size_t)ar0 * 128 + ks * 32 + kg * 8);
    const s16x8 g1 = *reinterpret_cast<const s16x8*>(agg + (size_t)ar1 * 128 + ks * 32 + kg * 8);
    const s16x8 h0 = *reinterpret_cast<const s16x8*>(hb + (size_t)ar0 * 128 + ks * 32 + kg * 8);
    const s16x8 h1 = *reinterpret_cast<const s16x8*>(hb + (size_t)ar1 * 128 + ks * 32 + kg * 8);
#pragma unroll
    for (int cf = 0; cf < 8; ++cf) {
      const s16x8 bwl = *reinterpret_cast<const s16x8*>(WTl + (size_t)(cf * 16 + lrow) * 128 + ks * 32 + kg * 8);
      const s16x8 bwr = *reinterpret_cast<const s16x8*>(WTr + (size_t)(cf * 16 + lrow) * 128 + ks * 32 + kg * 8);
      acc0[cf] = __builtin_amdgcn_mfma_f32_16x16x32_bf16(g0, bwl, acc0[cf], 0, 0, 0);
      acc0[cf] = __builtin_amdgcn_mfma_f32_16x16x32_bf16(h0, bwr, acc0[cf], 0, 0, 0);
      acc1[cf] = __builtin_amdgcn_mfma_f32_16x16x32_bf16(g1, bwl, acc1[cf], 0, 0, 0);
      acc1[cf] = __builtin_amdgcn_mfma_f32_16x16x32_bf16(h1, bwr, acc1[cf], 0, 0, 0);
    }
  }

  float bb[8], gm[8], gb[8];
#pragma unroll
  for (int cf = 0; cf < 8; ++cf) {
    const int c = cf * 16 + lrow;
    bb[cf] = bl[c];
    gm[cf] = lg[c];
    gb[cf] = lb[c];
  }

#pragma unroll
  for (int t = 0; t < 2; ++t) {
    const int base = tbase + t * 16;
#pragma unroll
    for (int j = 0; j < 4; ++j) {
      const int r = base + kg * 4 + j;
      const int rs = r < NN ? r : NN - 1;
      float v[8];
#pragma unroll
      for (int cf = 0; cf < 8; ++cf) {
        const int c = cf * 16 + lrow;
        const float rd = b2f(hb[(size_t)rs * 128 + c]);
        v[cf] = rd + fmaxf((t ? acc1[cf][j] : acc0[cf][j]) + bb[cf], 0.0f);
      }
      float s = 0.f;
#pragma unroll
      for (int cf = 0; cf < 8; ++cf) s += v[cf];
      s += __shfl_xor(s, 1); s += __shfl_xor(s, 2);
      s += __shfl_xor(s, 4); s += __shfl_xor(s, 8);
      const float mu = s * (1.0f / 128);
      float q = 0.f;
#pragma unroll
      for (int cf = 0; cf < 8; ++cf) { const float d = v[cf] - mu; q += d * d; }
      q += __shfl_xor(q, 1); q += __shfl_xor(q, 2);
      q += __shfl_xor(q, 4); q += __shfl_xor(q, 8);
      const float istd = rsqrtf(q * (1.0f / 128) + 1e-5f);
      if (r < NN) {
#pragma unroll
        for (int cf = 0; cf < 8; ++cf) {
          const int c = cf * 16 + lrow;
          const float o = (v[cf] - mu) * istd * gm[cf] + gb[cf];
          hb_out[(size_t)r * 128 + c] = f2b(o);
          if constexpr (LAST) outf[(size_t)r * 128 + c] = o;
        }
      }
    }
  }
}

// ---------------- fused classifier ----------------
__global__ __launch_bounds__(256) void k_cls(
    const u16* __restrict__ hb, const u16* __restrict__ WT1,
    const float* __restrict__ cb1, const u16* __restrict__ WT2,
    const float* __restrict__ cb2, float* __restrict__ logits) {
  __shared__ u16 t3[4][16][136];
  const int tid = threadIdx.x;
  const int wv = tid >> 6, ln = tid & 63;
  const int lrow = ln & 15, kg = ln >> 4;
  const int row0 = blockIdx.x * 64 + wv * 16;
  const int ar = min(row0 + lrow, NN - 1);

  f32x4 acc[8];
#pragma unroll
  for (int cf = 0; cf < 8; ++cf) acc[cf] = (f32x4){0.f, 0.f, 0.f, 0.f};
#pragma unroll
  for (int ks = 0; ks < 4; ++ks) {
    const s16x8 a = *reinterpret_cast<const s16x8*>(hb + (size_t)ar * 128 + ks * 32 + kg * 8);
#pragma unroll
    for (int cf = 0; cf < 8; ++cf) {
      const s16x8 bf = *reinterpret_cast<const s16x8*>(WT1 + (size_t)(cf * 16 + lrow) * 128 + ks * 32 + kg * 8);
      acc[cf] = __builtin_amdgcn_mfma_f32_16x16x32_bf16(a, bf, acc[cf], 0, 0, 0);
    }
  }
  float bb[8];
#pragma unroll
  for (int cf = 0; cf < 8; ++cf) bb[cf] = cb1[cf * 16 + lrow];
#pragma unroll
  for (int j = 0; j < 4; ++j) {
#pragma unroll
    for (int cf = 0; cf < 8; ++cf)
      t3[wv][kg * 4 + j][cf * 16 + lrow] = f2b(fmaxf(acc[cf][j] + bb[cf], 0.0f));
  }

  f32x4 acc2[3];
#pragma unroll
  for (int cf = 0; cf < 3; ++cf) acc2[cf] = (f32x4){0.f, 0.f, 0.f, 0.f};
#pragma unroll
  for (int ks = 0; ks < 4; ++ks) {
    const s16x8 a = *reinterpret_cast<const s16x8*>(&t3[wv][lrow][ks * 32 + kg * 8]);
#pragma unroll
    for (int cf = 0; cf < 3; ++cf) {
      const int bn = min(cf * 16 + lrow, CC - 1);
      const s16x8 bf = *reinterpret_cast<const s16x8*>(WT2 + (size_t)bn * 128 + ks * 32 + kg * 8);
      acc2[cf] = __builtin_amdgcn_mfma_f32_16x16x32_bf16(a, bf, acc2[cf], 0, 0, 0);
    }
  }
#pragma unroll
  for (int j = 0; j < 4; ++j) {
    const int r = row0 + kg * 4 + j;
    if (r < NN) {
#pragma unroll
      for (int cf = 0; cf < 3; ++cf) {
        const int c = cf * 16 + lrow;
        if (c < CC) logits[(size_t)r * CC + c] = acc2[cf][j] + cb2[c];
      }
    }
  }
}

}  // namespace

extern "C" void kernel_launch(void* const* d_in, const int* in_sizes, int n_in,
                              void* d_out, int out_size, void* d_ws, size_t ws_size,
                              hipStream_t stream) {
  (void)in_sizes; (void)n_in; (void)out_size; (void)ws_size;
  const float* x   = (const float*)d_in[0];
  const int*   ei  = (const int*)d_in[1];
  const float* pw1 = (const float*)d_in[2];
  const float* pb1 = (const float*)d_in[3];
  const float* pw2 = (const float*)d_in[4];
  const float* pb2 = (const float*)d_in[5];
  const float* ing = (const float*)d_in[6];
  const float* inb = (const float*)d_in[7];
  const float* swl = (const float*)d_in[8];
  const float* sbl = (const float*)d_in[9];
  const float* swr = (const float*)d_in[10];
  const float* lng = (const float*)d_in[11];
  const float* lnb = (const float*)d_in[12];
  const float* cw1 = (const float*)d_in[13];
  const float* cb1 = (const float*)d_in[14];
  const float* cw2 = (const float*)d_in[15];
  const float* cb2 = (const float*)d_in[16];

  float* out_logits = (float*)d_out;
  float* out_h = out_logits + (size_t)NN * CC;

  const size_t NNH = (size_t)NN * HH;
  u16*   hb   = (u16*)d_ws;                // 12.8 MB
  u16*   bufA = hb + NNH;                  // 12.8 MB (t1 / agg)
  u16*   wt   = bufA + NNH;                // 256 KB
  int*   cnt    = (int*)(wt + 8 * 16384);  // NN
  int*   cursor = cnt + NN;                // NN (adjacent: single memset)
  float* inv    = (float*)(cursor + NN);   // NN
  int*   rowptr = (int*)(inv + NN);        // NN+1
  int*   bsum   = rowptr + NN + 1;         // 256
  int*   colarr = bsum + 256;              // EE

  // ---- CSR build (multi-block scan; round-4's single-block scan was 81us on 1 CU) ----
  hipMemsetAsync(cnt, 0, 2 * NN * sizeof(int), stream);
  k_degree<<<(EE + 255) / 256, 256, 0, stream>>>(ei, cnt);
  k_scan_block<<<SCAN_NB, 256, 0, stream>>>(cnt, rowptr, bsum, inv);
  k_scan_tops<<<1, 256, 0, stream>>>(bsum);
  k_scan_add<<<SCAN_NB, 256, 0, stream>>>(rowptr, bsum);
  k_fill<<<(EE + 255) / 256, 256, 0, stream>>>(ei, rowptr, cursor, colarr);
  k_prep_w<<<(7 * 16384 + CC * 128 + 255) / 256, 256, 0, stream>>>(
      pw1, pw2, swl, swr, cw1, cw2, wt);

  const int MG = (NN + 127) / 128;  // 391
  // t1 = relu(x @ pw1 + pb1)           -> bufA (bf16), x converted on the fly
  k_in<POST_RELU, true><<<MG, 256, 0, stream>>>(
      nullptr, x, wt + 0 * 16384, pb1, nullptr, nullptr, bufA);
  // h = LN(t1 @ pw2 + pb2)             -> hb
  k_in<POST_LN, false><<<MG, 256, 0, stream>>>(
      bufA, nullptr, wt + 1 * 16384, pb2, ing, inb, hb);

  // layer 0
  k_gather4<<<(NN + 3) / 4, 256, 0, stream>>>(hb, rowptr, colarr, inv, bufA);
  k_sage<false><<<MG, 256, 0, stream>>>(
      bufA, hb, wt + 2 * 16384, wt + 4 * 16384, sbl, lng, lnb, hb, nullptr);
  // layer 1
  k_gather4<<<(NN + 3) / 4, 256, 0, stream>>>(hb, rowptr, colarr, inv, bufA);
  k_sage<true><<<MG, 256, 0, stream>>>(
      bufA, hb, wt + 3 * 16384, wt + 5 * 16384, sbl + HH, lng + HH, lnb + HH, hb, out_h);

  // classifier (fused)
  k_cls<<<(NN + 63) / 64, 256, 0, stream>>>(
      hb, wt + 6 * 16384, cb1, wt + 7 * 16384, cb2, out_logits);
}

// Round 6
// 237.578 us; speedup vs baseline: 3.9484x; 1.0812x over previous
//
#include <hip/hip_runtime.h>

// GNN encoder: input MLP + LN, 2x SAGEConv(mean) + ReLU + residual + LN, classifier MLP.
// Round 6:
//  - k_mlp: both input-MLP matmuls fused via LDS t1 tile [128][136] (pad-136 stride)
//  - k_sage_cls: layer-1 SAGE + classifier fused (h' -> LDS -> t3 -> logits), no hb write
//  - k_gather4: 2x4-edge software pipeline (2 independent gathers in flight per lane)
//  - CSR: multi-block hierarchical scan (round-5), inv fused into phase 1

namespace {

constexpr int NN = 50000;
constexpr int EE = 640000;
constexpr int HH = 128;
constexpr int CC = 40;
constexpr int SCAN_NB = (NN + 255) / 256;  // 196

typedef unsigned short u16;
typedef __attribute__((ext_vector_type(8))) short s16x8;
typedef __attribute__((ext_vector_type(8))) unsigned short u16x8;
typedef __attribute__((ext_vector_type(4))) float f32x4;

__device__ __forceinline__ float b2f(u16 h) {
  unsigned int u = ((unsigned int)h) << 16;
  return __builtin_bit_cast(float, u);
}
__device__ __forceinline__ u16 f2b(float f) {
  unsigned int u = __builtin_bit_cast(unsigned int, f);
  u += 0x7FFFu + ((u >> 16) & 1u);
  return (u16)(u >> 16);
}

// ---------------- CSR build ----------------
__global__ void k_degree(const int* __restrict__ ei, int* __restrict__ cnt) {
  int e = blockIdx.x * 256 + threadIdx.x;
  if (e < EE) atomicAdd(&cnt[ei[EE + e]], 1);
}

__global__ void k_scan_block(const int* __restrict__ cnt, int* __restrict__ rowptr,
                             int* __restrict__ bsum, float* __restrict__ inv) {
  __shared__ int s[256];
  const int t = threadIdx.x;
  const int i = blockIdx.x * 256 + t;
  const int v = i < NN ? cnt[i] : 0;
  s[t] = v;
  __syncthreads();
  for (int off = 1; off < 256; off <<= 1) {
    int add = t >= off ? s[t - off] : 0;
    __syncthreads();
    s[t] += add;
    __syncthreads();
  }
  if (i < NN) {
    rowptr[i] = s[t] - v;
    inv[i] = v > 0 ? 1.0f / (float)v : 0.0f;
  }
  if (t == 255) bsum[blockIdx.x] = s[255];
}

__global__ void k_scan_tops(int* __restrict__ bsum) {
  __shared__ int s[256];
  const int t = threadIdx.x;
  const int v = t < SCAN_NB ? bsum[t] : 0;
  s[t] = v;
  __syncthreads();
  for (int off = 1; off < 256; off <<= 1) {
    int add = t >= off ? s[t - off] : 0;
    __syncthreads();
    s[t] += add;
    __syncthreads();
  }
  if (t < SCAN_NB) bsum[t] = s[t] - v;
}

__global__ void k_scan_add(int* __restrict__ rowptr, const int* __restrict__ bsum) {
  const int i = blockIdx.x * 256 + threadIdx.x;
  if (i < NN) rowptr[i] += bsum[blockIdx.x];
  if (i == 0) rowptr[NN] = EE;
}

__global__ void k_fill(const int* __restrict__ ei, const int* __restrict__ rowptr,
                       int* __restrict__ cursor, int* __restrict__ col) {
  int e = blockIdx.x * 256 + threadIdx.x;
  if (e >= EE) return;
  int s = ei[e];
  int d = ei[EE + e];
  int pos = atomicAdd(&cursor[d], 1);
  col[rowptr[d] + pos] = s;
}

// transpose+cast all weights into wt slots {pw1,pw2,wl0,wl1,wr0,wr1,cw1,cw2T}
__global__ void k_prep_w(const float* __restrict__ pw1, const float* __restrict__ pw2,
                         const float* __restrict__ swl, const float* __restrict__ swr,
                         const float* __restrict__ cw1, const float* __restrict__ cw2,
                         u16* __restrict__ wt) {
  int flat = blockIdx.x * 256 + threadIdx.x;
  const int SEVEN = 7 * 16384;
  if (flat < SEVEN) {
    int id = flat >> 14;
    int off = flat & 16383;
    int n = off >> 7, k = off & 127;
    const float* s;
    switch (id) {
      case 0: s = pw1; break;
      case 1: s = pw2; break;
      case 2: s = swl; break;
      case 3: s = swl + 16384; break;
      case 4: s = swr; break;
      case 5: s = swr + 16384; break;
      default: s = cw1; break;
    }
    wt[(size_t)id * 16384 + n * 128 + k] = f2b(s[k * 128 + n]);
  } else {
    int off = flat - SEVEN;
    if (off < CC * 128) {
      int n = off >> 7, k = off & 127;
      wt[(size_t)7 * 16384 + n * 128 + k] = f2b(cw2[k * CC + n]);
    }
  }
}

// ---------------- aggregation: wave per node, pipelined 2x4 edges ----------------
__global__ __launch_bounds__(256) void k_gather4(
    const u16* __restrict__ hb, const int* __restrict__ rowptr,
    const int* __restrict__ col, const float* __restrict__ inv,
    u16* __restrict__ agg) {
  const int tid = threadIdx.x;
  const int wv = tid >> 6, ln = tid & 63;
  const int node = blockIdx.x * 4 + wv;
  if (node >= NN) return;
  const int start = rowptr[node];
  const int end = rowptr[node + 1];
  const int quarter = ln >> 4;
  const int cl = (ln & 15) * 8;
  float a[8] = {0.f, 0.f, 0.f, 0.f, 0.f, 0.f, 0.f, 0.f};
  int i = start;
  const int rem = end - start;
  const int pairs = rem >> 3;
  for (int p = 0; p < pairs; ++p) {
    const int s0 = col[i + quarter];
    const int s1 = col[i + 4 + quarter];
    const u16x8 v0 = *reinterpret_cast<const u16x8*>(&hb[(size_t)s0 * HH + cl]);
    const u16x8 v1 = *reinterpret_cast<const u16x8*>(&hb[(size_t)s1 * HH + cl]);
#pragma unroll
    for (int k = 0; k < 8; ++k) a[k] += b2f(v0[k]) + b2f(v1[k]);
    i += 8;
  }
  if (rem & 4) {
    const int s0 = col[i + quarter];
    const u16x8 v0 = *reinterpret_cast<const u16x8*>(&hb[(size_t)s0 * HH + cl]);
#pragma unroll
    for (int k = 0; k < 8; ++k) a[k] += b2f(v0[k]);
    i += 4;
  }
  if (i < end && quarter < end - i) {
    const int s0 = col[i + quarter];
    const u16x8 v0 = *reinterpret_cast<const u16x8*>(&hb[(size_t)s0 * HH + cl]);
#pragma unroll
    for (int k = 0; k < 8; ++k) a[k] += b2f(v0[k]);
  }
#pragma unroll
  for (int k = 0; k < 8; ++k) {
    a[k] += __shfl_xor(a[k], 16);
    a[k] += __shfl_xor(a[k], 32);
  }
  if (quarter == 0) {
    const float sc = inv[node];
    u16x8 o;
#pragma unroll
    for (int k = 0; k < 8; ++k) o[k] = f2b(a[k] * sc);
    *reinterpret_cast<u16x8*>(&agg[(size_t)node * HH + cl]) = o;
  }
}

// ---------------- fused input MLP: h = LN(relu(x@pw1+pb1)@pw2+pb2) ----------------
__global__ __launch_bounds__(256) void k_mlp(
    const float* __restrict__ x, const u16* __restrict__ WT1,
    const float* __restrict__ pb1, const u16* __restrict__ WT2,
    const float* __restrict__ pb2, const float* __restrict__ lg,
    const float* __restrict__ lb, u16* __restrict__ hb) {
  __shared__ u16 t1[128][136];
  const int tid = threadIdx.x;
  const int wv = tid >> 6, ln = tid & 63;
  const int lrow = ln & 15, kg = ln >> 4;
  const int tbase = blockIdx.x * 128 + wv * 32;
  const int lb0 = wv * 32;
  const int ar0 = min(tbase + lrow, NN - 1);
  const int ar1 = min(tbase + 16 + lrow, NN - 1);

  f32x4 acc0[8], acc1[8];
#pragma unroll
  for (int cf = 0; cf < 8; ++cf) {
    acc0[cf] = (f32x4){0.f, 0.f, 0.f, 0.f};
    acc1[cf] = (f32x4){0.f, 0.f, 0.f, 0.f};
  }

#pragma unroll
  for (int ks = 0; ks < 4; ++ks) {
    const float4* p0 = reinterpret_cast<const float4*>(x + (size_t)ar0 * 128 + ks * 32 + kg * 8);
    const float4* p1 = reinterpret_cast<const float4*>(x + (size_t)ar1 * 128 + ks * 32 + kg * 8);
    float4 x0 = p0[0], x1 = p0[1], y0 = p1[0], y1 = p1[1];
    s16x8 a0, a1;
    a0[0] = (short)f2b(x0.x); a0[1] = (short)f2b(x0.y); a0[2] = (short)f2b(x0.z); a0[3] = (short)f2b(x0.w);
    a0[4] = (short)f2b(x1.x); a0[5] = (short)f2b(x1.y); a0[6] = (short)f2b(x1.z); a0[7] = (short)f2b(x1.w);
    a1[0] = (short)f2b(y0.x); a1[1] = (short)f2b(y0.y); a1[2] = (short)f2b(y0.z); a1[3] = (short)f2b(y0.w);
    a1[4] = (short)f2b(y1.x); a1[5] = (short)f2b(y1.y); a1[6] = (short)f2b(y1.z); a1[7] = (short)f2b(y1.w);
#pragma unroll
    for (int cf = 0; cf < 8; ++cf) {
      const s16x8 bf = *reinterpret_cast<const s16x8*>(WT1 + (size_t)(cf * 16 + lrow) * 128 + ks * 32 + kg * 8);
      acc0[cf] = __builtin_amdgcn_mfma_f32_16x16x32_bf16(a0, bf, acc0[cf], 0, 0, 0);
      acc1[cf] = __builtin_amdgcn_mfma_f32_16x16x32_bf16(a1, bf, acc1[cf], 0, 0, 0);
    }
  }

  {
    float bb[8];
#pragma unroll
    for (int cf = 0; cf < 8; ++cf) bb[cf] = pb1[cf * 16 + lrow];
#pragma unroll
    for (int t = 0; t < 2; ++t)
#pragma unroll
      for (int j = 0; j < 4; ++j) {
        const int lr = lb0 + t * 16 + kg * 4 + j;
#pragma unroll
        for (int cf = 0; cf < 8; ++cf)
          t1[lr][cf * 16 + lrow] = f2b(fmaxf((t ? acc1[cf][j] : acc0[cf][j]) + bb[cf], 0.0f));
      }
  }
  __syncthreads();

  // phase 2: h = LN(t1 @ pw2 + pb2)
  f32x4 c0[8], c1[8];
#pragma unroll
  for (int cf = 0; cf < 8; ++cf) {
    c0[cf] = (f32x4){0.f, 0.f, 0.f, 0.f};
    c1[cf] = (f32x4){0.f, 0.f, 0.f, 0.f};
  }
#pragma unroll
  for (int ks = 0; ks < 4; ++ks) {
    const s16x8 a0 = *reinterpret_cast<const s16x8*>(&t1[lb0 + lrow][ks * 32 + kg * 8]);
    const s16x8 a1 = *reinterpret_cast<const s16x8*>(&t1[lb0 + 16 + lrow][ks * 32 + kg * 8]);
#pragma unroll
    for (int cf = 0; cf < 8; ++cf) {
      const s16x8 bf = *reinterpret_cast<const s16x8*>(WT2 + (size_t)(cf * 16 + lrow) * 128 + ks * 32 + kg * 8);
      c0[cf] = __builtin_amdgcn_mfma_f32_16x16x32_bf16(a0, bf, c0[cf], 0, 0, 0);
      c1[cf] = __builtin_amdgcn_mfma_f32_16x16x32_bf16(a1, bf, c1[cf], 0, 0, 0);
    }
  }

  float bb[8], gm[8], gb[8];
#pragma unroll
  for (int cf = 0; cf < 8; ++cf) {
    const int c = cf * 16 + lrow;
    bb[cf] = pb2[c];
    gm[cf] = lg[c];
    gb[cf] = lb[c];
  }
#pragma unroll
  for (int t = 0; t < 2; ++t)
#pragma unroll
    for (int j = 0; j < 4; ++j) {
      const int r = tbase + t * 16 + kg * 4 + j;
      float v[8];
#pragma unroll
      for (int cf = 0; cf < 8; ++cf) v[cf] = (t ? c1[cf][j] : c0[cf][j]) + bb[cf];
      float s = 0.f;
#pragma unroll
      for (int cf = 0; cf < 8; ++cf) s += v[cf];
      s += __shfl_xor(s, 1); s += __shfl_xor(s, 2);
      s += __shfl_xor(s, 4); s += __shfl_xor(s, 8);
      const float mu = s * (1.0f / 128);
      float q = 0.f;
#pragma unroll
      for (int cf = 0; cf < 8; ++cf) { const float d = v[cf] - mu; q += d * d; }
      q += __shfl_xor(q, 1); q += __shfl_xor(q, 2);
      q += __shfl_xor(q, 4); q += __shfl_xor(q, 8);
      const float istd = rsqrtf(q * (1.0f / 128) + 1e-5f);
      if (r < NN) {
#pragma unroll
        for (int cf = 0; cf < 8; ++cf)
          hb[(size_t)r * 128 + cf * 16 + lrow] = f2b((v[cf] - mu) * istd * gm[cf] + gb[cf]);
      }
    }
}

// ---------------- SAGE layer 0: h' = LN(h + relu(agg@WL + bl + h@WR)) -> hb ----------------
__global__ __launch_bounds__(256) void k_sage0(
    const u16* __restrict__ agg, const u16* __restrict__ hb,
    const u16* __restrict__ WTl, const u16* __restrict__ WTr,
    const float* __restrict__ bl, const float* __restrict__ lg,
    const float* __restrict__ lb, u16* __restrict__ hb_out) {
  const int tid = threadIdx.x;
  const int wv = tid >> 6, ln = tid & 63;
  const int lrow = ln & 15, kg = ln >> 4;
  const int tbase = blockIdx.x * 128 + wv * 32;
  const int ar0 = min(tbase + lrow, NN - 1);
  const int ar1 = min(tbase + 16 + lrow, NN - 1);

  f32x4 acc0[8], acc1[8];
#pragma unroll
  for (int cf = 0; cf < 8; ++cf) {
    acc0[cf] = (f32x4){0.f, 0.f, 0.f, 0.f};
    acc1[cf] = (f32x4){0.f, 0.f, 0.f, 0.f};
  }
#pragma unroll
  for (int ks = 0; ks < 4; ++ks) {
    const s16x8 g0 = *reinterpret_cast<const s16x8*>(agg + (size_t)ar0 * 128 + ks * 32 + kg * 8);
    const s16x8 g1 = *reinterpret_cast<const s16x8*>(agg + (size_t)ar1 * 128 + ks * 32 + kg * 8);
    const s16x8 h0 = *reinterpret_cast<const s16x8*>(hb + (size_t)ar0 * 128 + ks * 32 + kg * 8);
    const s16x8 h1 = *reinterpret_cast<const s16x8*>(hb + (size_t)ar1 * 128 + ks * 32 + kg * 8);
#pragma unroll
    for (int cf = 0; cf < 8; ++cf) {
      const s16x8 bwl = *reinterpret_cast<const s16x8*>(WTl + (size_t)(cf * 16 + lrow) * 128 + ks * 32 + kg * 8);
      const s16x8 bwr = *reinterpret_cast<const s16x8*>(WTr + (size_t)(cf * 16 + lrow) * 128 + ks * 32 + kg * 8);
      acc0[cf] = __builtin_amdgcn_mfma_f32_16x16x32_bf16(g0, bwl, acc0[cf], 0, 0, 0);
      acc0[cf] = __builtin_amdgcn_mfma_f32_16x16x32_bf16(h0, bwr, acc0[cf], 0, 0, 0);
      acc1[cf] = __builtin_amdgcn_mfma_f32_16x16x32_bf16(g1, bwl, acc1[cf], 0, 0, 0);
      acc1[cf] = __builtin_amdgcn_mfma_f32_16x16x32_bf16(h1, bwr, acc1[cf], 0, 0, 0);
    }
  }

  float bb[8], gm[8], gb[8];
#pragma unroll
  for (int cf = 0; cf < 8; ++cf) {
    const int c = cf * 16 + lrow;
    bb[cf] = bl[c];
    gm[cf] = lg[c];
    gb[cf] = lb[c];
  }
#pragma unroll
  for (int t = 0; t < 2; ++t)
#pragma unroll
    for (int j = 0; j < 4; ++j) {
      const int r = tbase + t * 16 + kg * 4 + j;
      const int rs = r < NN ? r : NN - 1;
      float v[8];
#pragma unroll
      for (int cf = 0; cf < 8; ++cf) {
        const int c = cf * 16 + lrow;
        v[cf] = b2f(hb[(size_t)rs * 128 + c]) +
                fmaxf((t ? acc1[cf][j] : acc0[cf][j]) + bb[cf], 0.0f);
      }
      float s = 0.f;
#pragma unroll
      for (int cf = 0; cf < 8; ++cf) s += v[cf];
      s += __shfl_xor(s, 1); s += __shfl_xor(s, 2);
      s += __shfl_xor(s, 4); s += __shfl_xor(s, 8);
      const float mu = s * (1.0f / 128);
      float q = 0.f;
#pragma unroll
      for (int cf = 0; cf < 8; ++cf) { const float d = v[cf] - mu; q += d * d; }
      q += __shfl_xor(q, 1); q += __shfl_xor(q, 2);
      q += __shfl_xor(q, 4); q += __shfl_xor(q, 8);
      const float istd = rsqrtf(q * (1.0f / 128) + 1e-5f);
      if (r < NN) {
#pragma unroll
        for (int cf = 0; cf < 8; ++cf)
          hb_out[(size_t)r * 128 + cf * 16 + lrow] = f2b((v[cf] - mu) * istd * gm[cf] + gb[cf]);
      }
    }
}

// ---------------- SAGE layer 1 + classifier fused ----------------
// h' = LN(h + relu(agg@WL + bl + h@WR)) -> out_h (f32) + LDS
// logits = relu(h'@cw1 + cb1) @ cw2 + cb2 (t3 overwrites h' rows in LDS, wave-private)
__global__ __launch_bounds__(256) void k_sage_cls(
    const u16* __restrict__ agg, const u16* __restrict__ hb,
    const u16* __restrict__ WTl, const u16* __restrict__ WTr,
    const float* __restrict__ bl, const float* __restrict__ lg,
    const float* __restrict__ lb,
    const u16* __restrict__ Wc1, const float* __restrict__ cb1,
    const u16* __restrict__ Wc2, const float* __restrict__ cb2,
    float* __restrict__ out_h, float* __restrict__ logits) {
  __shared__ u16 th[128][136];
  const int tid = threadIdx.x;
  const int wv = tid >> 6, ln = tid & 63;
  const int lrow = ln & 15, kg = ln >> 4;
  const int tbase = blockIdx.x * 128 + wv * 32;
  const int lb0 = wv * 32;
  const int ar0 = min(tbase + lrow, NN - 1);
  const int ar1 = min(tbase + 16 + lrow, NN - 1);

  f32x4 acc0[8], acc1[8];
#pragma unroll
  for (int cf = 0; cf < 8; ++cf) {
    acc0[cf] = (f32x4){0.f, 0.f, 0.f, 0.f};
    acc1[cf] = (f32x4){0.f, 0.f, 0.f, 0.f};
  }
#pragma unroll
  for (int ks = 0; ks < 4; ++ks) {
    const s16x8 g0 = *reinterpret_cast<const s16x8*>(agg + (size_t)ar0 * 128 + ks * 32 + kg * 8);
    const s16x8 g1 = *reinterpret_cast<const s16x8*>(agg + (size_t)ar1 * 128 + ks * 32 + kg * 8);
    const s16x8 h0 = *reinterpret_cast<const s16x8*>(hb + (size_t)ar0 * 128 + ks * 32 + kg * 8);
    const s16x8 h1 = *reinterpret_cast<const s16x8*>(hb + (size_t)ar1 * 128 + ks * 32 + kg * 8);
#pragma unroll
    for (int cf = 0; cf < 8; ++cf) {
      const s16x8 bwl = *reinterpret_cast<const s16x8*>(WTl + (size_t)(cf * 16 + lrow) * 128 + ks * 32 + kg * 8);
      const s16x8 bwr = *reinterpret_cast<const s16x8*>(WTr + (size_t)(cf * 16 + lrow) * 128 + ks * 32 + kg * 8);
      acc0[cf] = __builtin_amdgcn_mfma_f32_16x16x32_bf16(g0, bwl, acc0[cf], 0, 0, 0);
      acc0[cf] = __builtin_amdgcn_mfma_f32_16x16x32_bf16(h0, bwr, acc0[cf], 0, 0, 0);
      acc1[cf] = __builtin_amdgcn_mfma_f32_16x16x32_bf16(g1, bwl, acc1[cf], 0, 0, 0);
      acc1[cf] = __builtin_amdgcn_mfma_f32_16x16x32_bf16(h1, bwr, acc1[cf], 0, 0, 0);
    }
  }

  {
    float bb[8], gm[8], gb[8];
#pragma unroll
    for (int cf = 0; cf < 8; ++cf) {
      const int c = cf * 16 + lrow;
      bb[cf] = bl[c];
      gm[cf] = lg[c];
      gb[cf] = lb[c];
    }
#pragma unroll
    for (int t = 0; t < 2; ++t)
#pragma unroll
      for (int j = 0; j < 4; ++j) {
        const int r = tbase + t * 16 + kg * 4 + j;
        const int rs = r < NN ? r : NN - 1;
        const int lr = lb0 + t * 16 + kg * 4 + j;
        float v[8];
#pragma unroll
        for (int cf = 0; cf < 8; ++cf) {
          const int c = cf * 16 + lrow;
          v[cf] = b2f(hb[(size_t)rs * 128 + c]) +
                  fmaxf((t ? acc1[cf][j] : acc0[cf][j]) + bb[cf], 0.0f);
        }
        float s = 0.f;
#pragma unroll
        for (int cf = 0; cf < 8; ++cf) s += v[cf];
        s += __shfl_xor(s, 1); s += __shfl_xor(s, 2);
        s += __shfl_xor(s, 4); s += __shfl_xor(s, 8);
        const float mu = s * (1.0f / 128);
        float q = 0.f;
#pragma unroll
        for (int cf = 0; cf < 8; ++cf) { const float d = v[cf] - mu; q += d * d; }
        q += __shfl_xor(q, 1); q += __shfl_xor(q, 2);
        q += __shfl_xor(q, 4); q += __shfl_xor(q, 8);
        const float istd = rsqrtf(q * (1.0f / 128) + 1e-5f);
#pragma unroll
        for (int cf = 0; cf < 8; ++cf) {
          const int c = cf * 16 + lrow;
          const float o = (v[cf] - mu) * istd * gm[cf] + gb[cf];
          th[lr][c] = f2b(o);
          if (r < NN) out_h[(size_t)r * 128 + c] = o;
        }
      }
  }
  __syncthreads();

  // classifier phase: per wave, two 16-row tiles (rows wave-private in LDS)
  float cb1v[8];
#pragma unroll
  for (int cf = 0; cf < 8; ++cf) cb1v[cf] = cb1[cf * 16 + lrow];

#pragma unroll
  for (int t = 0; t < 2; ++t) {
    const int rb = lb0 + t * 16;
    f32x4 a3[8];
#pragma unroll
    for (int cf = 0; cf < 8; ++cf) a3[cf] = (f32x4){0.f, 0.f, 0.f, 0.f};
#pragma unroll
    for (int ks = 0; ks < 4; ++ks) {
      const s16x8 a = *reinterpret_cast<const s16x8*>(&th[rb + lrow][ks * 32 + kg * 8]);
#pragma unroll
      for (int cf = 0; cf < 8; ++cf) {
        const s16x8 bf = *reinterpret_cast<const s16x8*>(Wc1 + (size_t)(cf * 16 + lrow) * 128 + ks * 32 + kg * 8);
        a3[cf] = __builtin_amdgcn_mfma_f32_16x16x32_bf16(a, bf, a3[cf], 0, 0, 0);
      }
    }
    // t3 overwrites h' rows (only this wave reads them)
#pragma unroll
    for (int j = 0; j < 4; ++j)
#pragma unroll
      for (int cf = 0; cf < 8; ++cf)
        th[rb + kg * 4 + j][cf * 16 + lrow] = f2b(fmaxf(a3[cf][j] + cb1v[cf], 0.0f));

    f32x4 a2[3];
#pragma unroll
    for (int cf = 0; cf < 3; ++cf) a2[cf] = (f32x4){0.f, 0.f, 0.f, 0.f};
#pragma unroll
    for (int ks = 0; ks < 4; ++ks) {
      const s16x8 a = *reinterpret_cast<const s16x8*>(&th[rb + lrow][ks * 32 + kg * 8]);
#pragma unroll
      for (int cf = 0; cf < 3; ++cf) {
        const int bn = min(cf * 16 + lrow, CC - 1);
        const s16x8 bf = *reinterpret_cast<const s16x8*>(Wc2 + (size_t)bn * 128 + ks * 32 + kg * 8);
        a2[cf] = __builtin_amdgcn_mfma_f32_16x16x32_bf16(a, bf, a2[cf], 0, 0, 0);
      }
    }
#pragma unroll
    for (int j = 0; j < 4; ++j) {
      const int r = tbase + t * 16 + kg * 4 + j;
      if (r < NN) {
#pragma unroll
        for (int cf = 0; cf < 3; ++cf) {
          const int c = cf * 16 + lrow;
          if (c < CC) logits[(size_t)r * CC + c] = a2[cf][j] + cb2[c];
        }
      }
    }
  }
}

}  // namespace

extern "C" void kernel_launch(void* const* d_in, const int* in_sizes, int n_in,
                              void* d_out, int out_size, void* d_ws, size_t ws_size,
                              hipStream_t stream) {
  (void)in_sizes; (void)n_in; (void)out_size; (void)ws_size;
  const float* x   = (const float*)d_in[0];
  const int*   ei  = (const int*)d_in[1];
  const float* pw1 = (const float*)d_in[2];
  const float* pb1 = (const float*)d_in[3];
  const float* pw2 = (const float*)d_in[4];
  const float* pb2 = (const float*)d_in[5];
  const float* ing = (const float*)d_in[6];
  const float* inb = (const float*)d_in[7];
  const float* swl = (const float*)d_in[8];
  const float* sbl = (const float*)d_in[9];
  const float* swr = (const float*)d_in[10];
  const float* lng = (const float*)d_in[11];
  const float* lnb = (const float*)d_in[12];
  const float* cw1 = (const float*)d_in[13];
  const float* cb1 = (const float*)d_in[14];
  const float* cw2 = (const float*)d_in[15];
  const float* cb2 = (const float*)d_in[16];

  float* out_logits = (float*)d_out;
  float* out_h = out_logits + (size_t)NN * CC;

  const size_t NNH = (size_t)NN * HH;
  u16*   hb   = (u16*)d_ws;                // 12.8 MB
  u16*   bufA = hb + NNH;                  // 12.8 MB (agg)
  u16*   wt   = bufA + NNH;                // 256 KB
  int*   cnt    = (int*)(wt + 8 * 16384);  // NN
  int*   cursor = cnt + NN;                // NN (adjacent: single memset)
  float* inv    = (float*)(cursor + NN);   // NN
  int*   rowptr = (int*)(inv + NN);        // NN+1
  int*   bsum   = rowptr + NN + 1;         // 256
  int*   colarr = bsum + 256;              // EE

  // ---- CSR build ----
  hipMemsetAsync(cnt, 0, 2 * NN * sizeof(int), stream);
  k_degree<<<(EE + 255) / 256, 256, 0, stream>>>(ei, cnt);
  k_scan_block<<<SCAN_NB, 256, 0, stream>>>(cnt, rowptr, bsum, inv);
  k_scan_tops<<<1, 256, 0, stream>>>(bsum);
  k_scan_add<<<SCAN_NB, 256, 0, stream>>>(rowptr, bsum);
  k_fill<<<(EE + 255) / 256, 256, 0, stream>>>(ei, rowptr, cursor, colarr);
  k_prep_w<<<(7 * 16384 + CC * 128 + 255) / 256, 256, 0, stream>>>(
      pw1, pw2, swl, swr, cw1, cw2, wt);

  const int MG = (NN + 127) / 128;  // 391
  // h = LN(relu(x@pw1+pb1)@pw2+pb2)   -> hb
  k_mlp<<<MG, 256, 0, stream>>>(x, wt + 0 * 16384, pb1, wt + 1 * 16384, pb2, ing, inb, hb);

  // layer 0
  k_gather4<<<(NN + 3) / 4, 256, 0, stream>>>(hb, rowptr, colarr, inv, bufA);
  k_sage0<<<MG, 256, 0, stream>>>(
      bufA, hb, wt + 2 * 16384, wt + 4 * 16384, sbl, lng, lnb, hb);

  // layer 1 + classifier
  k_gather4<<<(NN + 3) / 4, 256, 0, stream>>>(hb, rowptr, colarr, inv, bufA);
  k_sage_cls<<<MG, 256, 0, stream>>>(
      bufA, hb, wt + 3 * 16384, wt + 5 * 16384, sbl + HH, lng + HH, lnb + HH,
      wt + 6 * 16384, cb1, wt + 7 * 16384, cb2, out_h, out_logits);
}